// Round 7
// baseline (82.828 us; speedup 1.0000x reference)
//
#include <hip/hip_runtime.h>
#include <hip/hip_bf16.h>

// Shapes (fixed by the reference)
#define NB 8
#define NS 1024
#define ND 512
#define NH 8
#define NDK 64

typedef __attribute__((ext_vector_type(8))) short bf16x8;
typedef __attribute__((ext_vector_type(4))) float f32x4;
typedef __attribute__((ext_vector_type(16))) float f32x16;

// scores are computed in exp2 domain: Q is pre-scaled by 0.125 * log2(e)
#define QSCALE 0.18033688011112042f
#define NEGBIG -3.0e38f

#define CVTPK(dst, a, b) \
    asm("v_cvt_pk_bf16_f32 %0, %1, %2" : "=v"(dst) : "v"(a), "v"(b))
#define PLSWAP(a, b) \
    asm("v_permlane32_swap_b32 %0, %1" : "+v"(a), "+v"(b))
#define GLOAD16(gp, lp)                                                        \
    __builtin_amdgcn_global_load_lds(                                          \
        (const __attribute__((address_space(1))) unsigned*)(gp),               \
        (__attribute__((address_space(3))) unsigned*)(lp), 16, 0, 0)
#define VMCNT0() asm volatile("s_waitcnt vmcnt(0)" ::: "memory")
#define SBAR() __builtin_amdgcn_s_barrier()
#define SCHED0() __builtin_amdgcn_sched_barrier(0)

__device__ __forceinline__ unsigned short bfround(float f) {
    union { float f; unsigned u; } v; v.f = f;
    unsigned u = v.u;
    u += 0x7fffu + ((u >> 16) & 1u);
    return (unsigned short)(u >> 16);
}

// ---------------------------------------------------------------------------
// Fragment-major global layouts for attention operands (16B chunk = 8 shorts;
// a wave's chunk load is 64 lanes x 16B fully coalesced).
// ---------------------------------------------------------------------------
__device__ __forceinline__ size_t qf_off(int s, int dk) {
    return ((size_t)(((s >> 5) * 4 + (dk >> 4)) * 64 + ((dk >> 3) & 1) * 32 + (s & 31)) << 3) + (dk & 7);
}
__device__ __forceinline__ size_t kf_off(int s, int dk) {
    return ((size_t)(((s >> 6) * 8 + ((s >> 5) & 1) * 4 + (dk >> 4)) * 64 + ((dk >> 3) & 1) * 32 + (s & 31)) << 3) + (dk & 7);
}
__device__ __forceinline__ size_t vf_off(int s, int dk) {
    return ((size_t)(((s >> 6) * 8 + (dk >> 5) * 4 + ((s >> 4) & 3)) * 64 + ((s >> 3) & 1) * 32 + (dk & 31)) << 3) + (s & 7);
}

// ---------------------------------------------------------------------------
// Kernel 1: transpose + convert the four 512x512 fp32 weights ([in][out]) into
// bf16 Wt[out][in].
// ---------------------------------------------------------------------------
__global__ __launch_bounds__(256) void wt_kernel(const float* __restrict__ W0,
                                                 const float* __restrict__ W1,
                                                 const float* __restrict__ W2,
                                                 const float* __restrict__ W3,
                                                 unsigned short* __restrict__ wt) {
    __shared__ float sh[64][65];
    const int z = blockIdx.z;
    const float* W = z == 0 ? W0 : z == 1 ? W1 : z == 2 ? W2 : W3;
    unsigned short* out = wt + (size_t)z * ND * ND;
    const int o0 = blockIdx.x * 64, i0 = blockIdx.y * 64;
    const int tx = threadIdx.x & 63;
    const int ty = threadIdx.x >> 6;  // 0..3
    #pragma unroll
    for (int rr = 0; rr < 16; ++rr) {
        const int row = ty * 16 + rr;  // local i
        sh[row][tx] = W[(size_t)(i0 + row) * ND + o0 + tx];
    }
    __syncthreads();
    #pragma unroll
    for (int rr = 0; rr < 16; ++rr) {
        const int row = ty * 16 + rr;  // local o
        out[(size_t)(o0 + row) * ND + i0 + tx] = bfround(sh[tx][row]);
    }
}

// ---------------------------------------------------------------------------
// Kernel 2: QKV projection GEMM, 2-phase double-buffered pipeline (T3 minimum
// recipe): STAGE(next tile) issued BEFORE compute(current); raw s_barrier +
// inline vmcnt(0) only at phase end, so next-tile loads fly under the
// ds_read/cvt/MFMA of the current tile (the R6 structure force-drained vmcnt
// before every barrier -> fully serial K-steps, MfmaUtil 9.7%).
// Tile 128x128, BK=32, 4 waves (2x2), wave-tile 64x64. A staged fp32 with
// 16B-unit XOR swizzle on the global source; bf16 convert at fragment read.
// ---------------------------------------------------------------------------
__global__ __launch_bounds__(256) void gemm_qkv(
    const float* __restrict__ A0, const float* __restrict__ A1, const float* __restrict__ A2,
    const unsigned short* __restrict__ wt,
    const float* __restrict__ b0, const float* __restrict__ b1, const float* __restrict__ b2,
    unsigned short* __restrict__ outb) {
    __shared__ float Asf[2][128 * 32];           // 2 x 16 KB
    __shared__ unsigned short Bs[2][128 * 32];   // 2 x 8 KB
    const int t = threadIdx.x;
    const int lane = t & 63, w = t >> 6;
    const int wr = w >> 1, wc = w & 1;
    const int lr = lane & 15, lg = lane >> 4;
    const int bid = blockIdx.x;               // 768 blocks
    const int u = (bid & 7) * 96 + (bid >> 3);
    const int xt = u & 3, yt = (u >> 2) & 63, z = u >> 8;
    const float* A = z == 0 ? A0 : z == 1 ? A1 : A2;
    const float* bias = z == 0 ? b0 : z == 1 ? b1 : b2;
    const unsigned short* Wt = wt + (size_t)z * ND * ND;
    unsigned short* outp = outb + (size_t)z * NB * NH * NS * NDK;
    const int m0 = yt * 128, n0 = xt * 128;

    // per-lane staging geometry (constant across ksteps)
    const int a_row = w * 32 + (lane >> 3);             // + j*8
    const int a_gc = ((lane & 7) ^ (lane >> 3)) << 2;   // swizzled fp32 col
    const int b_row = w * 32 + (lane >> 2);             // + j*16
    const int b_gc = (lane & 3) * 8;

    f32x4 acc[4][4];
    #pragma unroll
    for (int i = 0; i < 4; ++i)
        #pragma unroll
        for (int j = 0; j < 4; ++j) acc[i][j] = (f32x4){0.f, 0.f, 0.f, 0.f};

#define QKV_STAGE(p, kt) do {                                                  \
        const int _k0 = (kt) * 32;                                             \
        GLOAD16(A + (size_t)(m0 + a_row + 0)  * ND + _k0 + a_gc, &Asf[p][(w * 4 + 0) * 256]); \
        GLOAD16(A + (size_t)(m0 + a_row + 8)  * ND + _k0 + a_gc, &Asf[p][(w * 4 + 1) * 256]); \
        GLOAD16(A + (size_t)(m0 + a_row + 16) * ND + _k0 + a_gc, &Asf[p][(w * 4 + 2) * 256]); \
        GLOAD16(A + (size_t)(m0 + a_row + 24) * ND + _k0 + a_gc, &Asf[p][(w * 4 + 3) * 256]); \
        GLOAD16(Wt + (size_t)(n0 + b_row + 0)  * ND + _k0 + b_gc, &Bs[p][(w * 2 + 0) * 512]); \
        GLOAD16(Wt + (size_t)(n0 + b_row + 16) * ND + _k0 + b_gc, &Bs[p][(w * 2 + 1) * 512]); \
    } while (0)

#define QKV_COMPUTE(p) do {                                                    \
        const float* _Ab = &Asf[p][0];                                         \
        const unsigned short* _Bb = &Bs[p][0];                                 \
        bf16x8 af[4], bfr[4];                                                  \
        _Pragma("unroll")                                                      \
        for (int mi = 0; mi < 4; ++mi) {                                       \
            const int r = wr * 64 + mi * 16 + lr;                              \
            const int u0 = (2 * lg) ^ (lr & 7);                                \
            const f32x4 x0 = *(const f32x4*)(_Ab + r * 32 + u0 * 4);           \
            const f32x4 x1 = *(const f32x4*)(_Ab + r * 32 + (u0 ^ 1) * 4);     \
            unsigned c0, c1, c2, c3;                                           \
            CVTPK(c0, x0[0], x0[1]); CVTPK(c1, x0[2], x0[3]);                  \
            CVTPK(c2, x1[0], x1[1]); CVTPK(c3, x1[2], x1[3]);                  \
            union { unsigned uu[4]; bf16x8 v; } cc;                            \
            cc.uu[0] = c0; cc.uu[1] = c1; cc.uu[2] = c2; cc.uu[3] = c3;        \
            af[mi] = cc.v;                                                     \
        }                                                                      \
        _Pragma("unroll")                                                      \
        for (int nj = 0; nj < 4; ++nj)                                         \
            bfr[nj] = *(const bf16x8*)(_Bb + (wc * 64 + nj * 16 + lr) * 32 + lg * 8); \
        __builtin_amdgcn_s_setprio(1);                                         \
        _Pragma("unroll")                                                      \
        for (int mi = 0; mi < 4; ++mi)                                         \
            _Pragma("unroll")                                                  \
            for (int nj = 0; nj < 4; ++nj)                                     \
                acc[mi][nj] = __builtin_amdgcn_mfma_f32_16x16x32_bf16(         \
                    af[mi], bfr[nj], acc[mi][nj], 0, 0, 0);                    \
        __builtin_amdgcn_s_setprio(0);                                         \
    } while (0)

    QKV_STAGE(0, 0);
    VMCNT0();
    SBAR();
    #pragma unroll 1
    for (int ii = 0; ii < 8; ++ii) {
        QKV_STAGE(1, 2 * ii + 1);
        SCHED0();
        QKV_COMPUTE(0);
        SCHED0();
        VMCNT0();
        SBAR();
        if (ii < 7) { QKV_STAGE(0, 2 * ii + 2); }
        SCHED0();
        QKV_COMPUTE(1);
        SCHED0();
        VMCNT0();
        SBAR();
    }
#undef QKV_STAGE
#undef QKV_COMPUTE

    const float osc = z == 0 ? QSCALE : 1.0f;
    #pragma unroll
    for (int mi = 0; mi < 4; ++mi) {
        #pragma unroll
        for (int nj = 0; nj < 4; ++nj) {
            const int n = n0 + wc * 64 + nj * 16 + lr;
            const float bv = bias[n];
            #pragma unroll
            for (int r = 0; r < 4; ++r) {
                const int m = m0 + wr * 64 + mi * 16 + lg * 4 + r;
                const float val = (acc[mi][nj][r] + bv) * osc;
                const int bb = m >> 10, s = m & 1023;    // m = b*S + s
                const int hh = n >> 6, dk = n & 63;      // n = h*64 + dk
                const size_t off = z == 0 ? qf_off(s, dk)
                                 : z == 1 ? kf_off(s, dk)
                                          : vf_off(s, dk);
                outp[((size_t)(bb * NH + hh) << 16) + off] = bfround(val);
            }
        }
    }
}

// ---------------------------------------------------------------------------
// Kernel 4: output projection GEMM, same 2-phase pipeline. Tile 128x64
// (512 blocks), BK=32, 4 waves (2x2), wave-tile 64x32. fp32 output.
// ---------------------------------------------------------------------------
__global__ __launch_bounds__(256) void gemm_out(
    const unsigned short* __restrict__ Xb, const unsigned short* __restrict__ Wt,
    const float* __restrict__ bo, float* __restrict__ outp) {
    __shared__ unsigned short As2[2][128 * 32];   // 2 x 8 KB
    __shared__ unsigned short Bs2[2][64 * 32];    // 2 x 4 KB
    const int t = threadIdx.x;
    const int lane = t & 63, w = t >> 6;
    const int wr = w >> 1, wc = w & 1;
    const int lr = lane & 15, lg = lane >> 4;
    const int bid = blockIdx.x;               // 512 blocks
    const int u = (bid & 7) * 64 + (bid >> 3);
    const int xt = u & 7, yt = u >> 3;
    const int m0 = yt * 128, n0 = xt * 64;

    const int a_row = w * 32 + (lane >> 2);   // + j*16
    const int b_row = w * 16 + (lane >> 2);
    const int gc = (lane & 3) * 8;

    f32x4 acc[4][2];
    #pragma unroll
    for (int i = 0; i < 4; ++i)
        #pragma unroll
        for (int j = 0; j < 2; ++j) acc[i][j] = (f32x4){0.f, 0.f, 0.f, 0.f};

#define OUT_STAGE(p, kt) do {                                                  \
        const int _k0 = (kt) * 32;                                             \
        GLOAD16(Xb + (size_t)(m0 + a_row + 0)  * ND + _k0 + gc, &As2[p][(w * 2 + 0) * 512]); \
        GLOAD16(Xb + (size_t)(m0 + a_row + 16) * ND + _k0 + gc, &As2[p][(w * 2 + 1) * 512]); \
        GLOAD16(Wt + (size_t)(n0 + b_row) * ND + _k0 + gc, &Bs2[p][w * 512]);  \
    } while (0)

#define OUT_COMPUTE(p) do {                                                    \
        const unsigned short* _Ab = &As2[p][0];                                \
        const unsigned short* _Bb = &Bs2[p][0];                                \
        bf16x8 af[4], bfr[2];                                                  \
        _Pragma("unroll")                                                      \
        for (int mi = 0; mi < 4; ++mi)                                         \
            af[mi] = *(const bf16x8*)(_Ab + (wr * 64 + mi * 16 + lr) * 32 + lg * 8); \
        _Pragma("unroll")                                                      \
        for (int nj = 0; nj < 2; ++nj)                                         \
            bfr[nj] = *(const bf16x8*)(_Bb + (wc * 32 + nj * 16 + lr) * 32 + lg * 8); \
        __builtin_amdgcn_s_setprio(1);                                         \
        _Pragma("unroll")                                                      \
        for (int mi = 0; mi < 4; ++mi)                                         \
            _Pragma("unroll")                                                  \
            for (int nj = 0; nj < 2; ++nj)                                     \
                acc[mi][nj] = __builtin_amdgcn_mfma_f32_16x16x32_bf16(         \
                    af[mi], bfr[nj], acc[mi][nj], 0, 0, 0);                    \
        __builtin_amdgcn_s_setprio(0);                                         \
    } while (0)

    OUT_STAGE(0, 0);
    VMCNT0();
    SBAR();
    #pragma unroll 1
    for (int ii = 0; ii < 8; ++ii) {
        OUT_STAGE(1, 2 * ii + 1);
        SCHED0();
        OUT_COMPUTE(0);
        SCHED0();
        VMCNT0();
        SBAR();
        if (ii < 7) { OUT_STAGE(0, 2 * ii + 2); }
        SCHED0();
        OUT_COMPUTE(1);
        SCHED0();
        VMCNT0();
        SBAR();
    }
#undef OUT_STAGE
#undef OUT_COMPUTE

    #pragma unroll
    for (int mi = 0; mi < 4; ++mi) {
        #pragma unroll
        for (int nj = 0; nj < 2; ++nj) {
            const int n = n0 + wc * 32 + nj * 16 + lr;
            const float bv = bo[n];
            #pragma unroll
            for (int r = 0; r < 4; ++r) {
                const int m = m0 + wr * 64 + mi * 16 + lg * 4 + r;
                outp[(size_t)m * ND + n] = acc[mi][nj][r] + bv;
            }
        }
    }
}

// ---------------------------------------------------------------------------
// Kernel 3: flash attention (unchanged from R5/R6 — fragment-major coalesced
// loads, swapped-operand 32x32 MFMA, in-register softmax, K double-buffer).
// ---------------------------------------------------------------------------
struct AttnState {
    f32x16 acc0, acc1;
    float m_st, l_st;
};

__device__ __forceinline__ void attn_step(const bf16x8 (&kf)[8], const bf16x8 (&vv)[8],
                                          const bf16x8 (&qf)[4], int mval,
                                          float* __restrict__ brow, int lane, int hi,
                                          AttnState& st) {
    brow[lane] = mval ? 0.f : NEGBIG;

    f32x16 sc0 = {}, sc1 = {};
    __builtin_amdgcn_s_setprio(1);
    sc0 = __builtin_amdgcn_mfma_f32_32x32x16_bf16(kf[0], qf[0], sc0, 0, 0, 0);
    sc1 = __builtin_amdgcn_mfma_f32_32x32x16_bf16(kf[4], qf[0], sc1, 0, 0, 0);
    sc0 = __builtin_amdgcn_mfma_f32_32x32x16_bf16(kf[1], qf[1], sc0, 0, 0, 0);
    sc1 = __builtin_amdgcn_mfma_f32_32x32x16_bf16(kf[5], qf[1], sc1, 0, 0, 0);
    sc0 = __builtin_amdgcn_mfma_f32_32x32x16_bf16(kf[2], qf[2], sc0, 0, 0, 0);
    sc1 = __builtin_amdgcn_mfma_f32_32x32x16_bf16(kf[6], qf[2], sc1, 0, 0, 0);
    sc0 = __builtin_amdgcn_mfma_f32_32x32x16_bf16(kf[3], qf[3], sc0, 0, 0, 0);
    sc1 = __builtin_amdgcn_mfma_f32_32x32x16_bf16(kf[7], qf[3], sc1, 0, 0, 0);
    __builtin_amdgcn_s_setprio(0);

    {
        const float* bl = brow + 4 * hi;
        #pragma unroll
        for (int mm = 0; mm < 4; ++mm) {
            const f32x4 bv0 = *(const f32x4*)(bl + 8 * mm);
            const f32x4 bv1 = *(const f32x4*)(bl + 32 + 8 * mm);
            #pragma unroll
            for (int c = 0; c < 4; ++c) {
                sc0[4 * mm + c] += bv0[c];
                sc1[4 * mm + c] += bv1[c];
            }
        }
    }

    float tv[16];
    #pragma unroll
    for (int r = 0; r < 16; ++r) tv[r] = fmaxf(sc0[r], sc1[r]);
    #pragma unroll
    for (int s = 8; s > 0; s >>= 1)
        #pragma unroll
        for (int r = 0; r < 16; ++r)
            if (r < s) tv[r] = fmaxf(tv[r], tv[r + s]);
    const float mx = fmaxf(tv[0], __shfl_xor(tv[0], 32));
    const float mn = fmaxf(st.m_st, mx);

    #pragma unroll
    for (int r = 0; r < 16; ++r) {
        sc0[r] = __builtin_amdgcn_exp2f(sc0[r] - mn);
        sc1[r] = __builtin_amdgcn_exp2f(sc1[r] - mn);
    }
    #pragma unroll
    for (int r = 0; r < 16; ++r) tv[r] = sc0[r] + sc1[r];
    #pragma unroll
    for (int s = 8; s > 0; s >>= 1)
        #pragma unroll
        for (int r = 0; r < 16; ++r)
            if (r < s) tv[r] += tv[r + s];
    const float rs = tv[0] + __shfl_xor(tv[0], 32);

    const bool ch = mn > st.m_st;
    if (__any(ch)) {
        const float f = __builtin_amdgcn_exp2f(st.m_st - mn);
        st.l_st = st.l_st * f + rs;
        st.m_st = mn;
        #pragma unroll
        for (int r = 0; r < 16; ++r) { st.acc0[r] *= f; st.acc1[r] *= f; }
    } else {
        st.l_st += rs;
    }

    union U8 { unsigned u[4]; bf16x8 v; };
    bf16x8 pA0, pA1, pB0, pB1;
    {
        unsigned w00, w01, w10, w11, w20, w21, w30, w31;
        CVTPK(w00, sc0[0], sc0[1]);  CVTPK(w01, sc0[2], sc0[3]);
        CVTPK(w10, sc0[4], sc0[5]);  CVTPK(w11, sc0[6], sc0[7]);
        CVTPK(w20, sc0[8], sc0[9]);  CVTPK(w21, sc0[10], sc0[11]);
        CVTPK(w30, sc0[12], sc0[13]); CVTPK(w31, sc0[14], sc0[15]);
        PLSWAP(w00, w10); PLSWAP(w01, w11);
        PLSWAP(w20, w30); PLSWAP(w21, w31);
        U8 f0; f0.u[0] = w00; f0.u[1] = w01; f0.u[2] = w10; f0.u[3] = w11;
        U8 f1; f1.u[0] = w20; f1.u[1] = w21; f1.u[2] = w30; f1.u[3] = w31;
        pA0 = f0.v; pA1 = f1.v;
    }
    {
        unsigned w00, w01, w10, w11, w20, w21, w30, w31;
        CVTPK(w00, sc1[0], sc1[1]);  CVTPK(w01, sc1[2], sc1[3]);
        CVTPK(w10, sc1[4], sc1[5]);  CVTPK(w11, sc1[6], sc1[7]);
        CVTPK(w20, sc1[8], sc1[9]);  CVTPK(w21, sc1[10], sc1[11]);
        CVTPK(w30, sc1[12], sc1[13]); CVTPK(w31, sc1[14], sc1[15]);
        PLSWAP(w00, w10); PLSWAP(w01, w11);
        PLSWAP(w20, w30); PLSWAP(w21, w31);
        U8 f0; f0.u[0] = w00; f0.u[1] = w01; f0.u[2] = w10; f0.u[3] = w11;
        U8 f1; f1.u[0] = w20; f1.u[1] = w21; f1.u[2] = w30; f1.u[3] = w31;
        pB0 = f0.v; pB1 = f1.v;
    }

    __builtin_amdgcn_s_setprio(1);
    st.acc0 = __builtin_amdgcn_mfma_f32_32x32x16_bf16(vv[0], pA0, st.acc0, 0, 0, 0);
    st.acc1 = __builtin_amdgcn_mfma_f32_32x32x16_bf16(vv[4], pA0, st.acc1, 0, 0, 0);
    st.acc0 = __builtin_amdgcn_mfma_f32_32x32x16_bf16(vv[1], pA1, st.acc0, 0, 0, 0);
    st.acc1 = __builtin_amdgcn_mfma_f32_32x32x16_bf16(vv[5], pA1, st.acc1, 0, 0, 0);
    st.acc0 = __builtin_amdgcn_mfma_f32_32x32x16_bf16(vv[2], pB0, st.acc0, 0, 0, 0);
    st.acc1 = __builtin_amdgcn_mfma_f32_32x32x16_bf16(vv[6], pB0, st.acc1, 0, 0, 0);
    st.acc0 = __builtin_amdgcn_mfma_f32_32x32x16_bf16(vv[3], pB1, st.acc0, 0, 0, 0);
    st.acc1 = __builtin_amdgcn_mfma_f32_32x32x16_bf16(vv[7], pB1, st.acc1, 0, 0, 0);
    __builtin_amdgcn_s_setprio(0);
}

__global__ __launch_bounds__(256, 2) void attn_kernel(const unsigned short* __restrict__ QF,
                                                      const unsigned short* __restrict__ KF,
                                                      const unsigned short* __restrict__ VF,
                                                      const int* __restrict__ mask,
                                                      unsigned short* __restrict__ Xb) {
    __shared__ float bias_lds[4][64];
    const int t = threadIdx.x;
    const int lane = t & 63, w = t >> 6;
    const int q32 = lane & 31, hi = lane >> 5;
    const int bid = blockIdx.x;                  // 512 blocks
    const int u = (bid & 7) * 64 + (bid >> 3);
    const int bh = u >> 3, xq = u & 7;
    const int b = bh >> 3, h = bh & 7;
    const int q = xq * 128 + w * 32 + q32;
    const unsigned short* QFh = QF + ((size_t)bh << 16);
    const unsigned short* KFh = KF + ((size_t)bh << 16);
    const unsigned short* VFh = VF + ((size_t)bh << 16);
    const int* mk = mask + b * NS;
    float* brow = &bias_lds[w][0];

    bf16x8 qf[4];
    {
        const unsigned short* Qp = QFh + (size_t)(xq * 16 + w * 4) * 512 + lane * 8;
        qf[0] = *(const bf16x8*)(Qp + 0 * 512);
        qf[1] = *(const bf16x8*)(Qp + 1 * 512);
        qf[2] = *(const bf16x8*)(Qp + 2 * 512);
        qf[3] = *(const bf16x8*)(Qp + 3 * 512);
    }

    AttnState st;
    st.acc0 = (f32x16){}; st.acc1 = (f32x16){};
    st.m_st = -1.0e30f; st.l_st = 0.f;

    bf16x8 kA[8], kB[8], vv[8];

#define LOADK(dst, itx) do {                                                   \
        const unsigned short* _p = KFh + (size_t)(itx) * 4096 + lane * 8;      \
        dst[0] = *(const bf16x8*)(_p + 0 * 512);                               \
        dst[1] = *(const bf16x8*)(_p + 1 * 512);                               \
        dst[2] = *(const bf16x8*)(_p + 2 * 512);                               \
        dst[3] = *(const bf16x8*)(_p + 3 * 512);                               \
        dst[4] = *(const bf16x8*)(_p + 4 * 512);                               \
        dst[5] = *(const bf16x8*)(_p + 5 * 512);                               \
        dst[6] = *(const bf16x8*)(_p + 6 * 512);                               \
        dst[7] = *(const bf16x8*)(_p + 7 * 512);                               \
    } while (0)

#define LOADV(dst, itx) do {                                                   \
        const unsigned short* _p = VFh + (size_t)(itx) * 4096 + lane * 8;      \
        dst[0] = *(const bf16x8*)(_p + 0 * 512);                               \
        dst[1] = *(const bf16x8*)(_p + 1 * 512);                               \
        dst[2] = *(const bf16x8*)(_p + 2 * 512);                               \
        dst[3] = *(const bf16x8*)(_p + 3 * 512);                               \
        dst[4] = *(const bf16x8*)(_p + 4 * 512);                               \
        dst[5] = *(const bf16x8*)(_p + 5 * 512);                               \
        dst[6] = *(const bf16x8*)(_p + 6 * 512);                               \
        dst[7] = *(const bf16x8*)(_p + 7 * 512);                               \
    } while (0)

    LOADK(kA, 0);
    #pragma unroll 1
    for (int ii = 0; ii < 8; ++ii) {
        const int itE = ii * 2, itO = itE + 1;
        const int mE = mk[itE * 64 + lane];
        LOADV(vv, itE);
        LOADK(kB, itO);
        __builtin_amdgcn_sched_barrier(0);
        attn_step(kA, vv, qf, mE, brow, lane, hi, st);
        const int mO = mk[itO * 64 + lane];
        const int itN = itO + 1 > 15 ? 15 : itO + 1;
        LOADV(vv, itO);
        LOADK(kA, itN);
        __builtin_amdgcn_sched_barrier(0);
        attn_step(kB, vv, qf, mO, brow, lane, hi, st);
    }
#undef LOADK
#undef LOADV

    const float inv = st.l_st > 0.f ? 1.f / st.l_st : 0.f;
    unsigned short* Xp = Xb + (size_t)(b * NS + q) * ND + h * 64 + 4 * hi;
    #pragma unroll
    for (int mm = 0; mm < 4; ++mm) {
        unsigned w0, w1;
        CVTPK(w0, st.acc0[4 * mm] * inv, st.acc0[4 * mm + 1] * inv);
        CVTPK(w1, st.acc0[4 * mm + 2] * inv, st.acc0[4 * mm + 3] * inv);
        uint2 pv; pv.x = w0; pv.y = w1;
        *(uint2*)(Xp + 8 * mm) = pv;
        CVTPK(w0, st.acc1[4 * mm] * inv, st.acc1[4 * mm + 1] * inv);
        CVTPK(w1, st.acc1[4 * mm + 2] * inv, st.acc1[4 * mm + 3] * inv);
        pv.x = w0; pv.y = w1;
        *(uint2*)(Xp + 32 + 8 * mm) = pv;
    }
}

// ---------------------------------------------------------------------------
// Host launcher. Workspace (bf16 elements): wt(4*512*512), QF, KF, VF, Xb.
// ---------------------------------------------------------------------------
extern "C" void kernel_launch(void* const* d_in, const int* in_sizes, int n_in,
                              void* d_out, int out_size, void* d_ws, size_t ws_size,
                              hipStream_t stream) {
    const float* query = (const float*)d_in[0];
    const float* key   = (const float*)d_in[1];
    const float* value = (const float*)d_in[2];
    const int*   mask  = (const int*)d_in[3];
    const float* Wq = (const float*)d_in[4];
    const float* bq = (const float*)d_in[5];
    const float* Wk = (const float*)d_in[6];
    const float* bk = (const float*)d_in[7];
    const float* Wv = (const float*)d_in[8];
    const float* bv = (const float*)d_in[9];
    const float* Wo = (const float*)d_in[10];
    const float* bo = (const float*)d_in[11];

    const size_t HEADSZ = (size_t)NB * NH * NS * NDK;  // 4194304
    unsigned short* wt = (unsigned short*)d_ws;
    unsigned short* QFb = wt + (size_t)4 * ND * ND;
    unsigned short* KFb = QFb + HEADSZ;
    unsigned short* VFb = KFb + HEADSZ;
    unsigned short* Xb  = VFb + HEADSZ;

    // 1. weights -> bf16, transposed
    wt_kernel<<<dim3(8, 8, 4), 256, 0, stream>>>(Wq, Wk, Wv, Wo, wt);

    // 2. QKV projections into fragment-major layouts (z = q/k/v)
    gemm_qkv<<<768, 256, 0, stream>>>(query, key, value, wt, bq, bk, bv, QFb);

    // 3. attention (512 blocks, 4 waves each, no barriers)
    attn_kernel<<<512, 256, 0, stream>>>(QFb, KFb, VFb, mask, Xb);

    // 4. output projection (fp32 out)
    gemm_out<<<512, 256, 0, stream>>>(Xb, wt + (size_t)3 * ND * ND, bo, (float*)d_out);
}

// Round 8
// 82.080 us; speedup vs baseline: 1.0091x; 1.0091x over previous
//
#include <hip/hip_runtime.h>
#include <hip/hip_bf16.h>

// Shapes (fixed by the reference)
#define NB 8
#define NS 1024
#define ND 512
#define NH 8
#define NDK 64

typedef __attribute__((ext_vector_type(8))) short bf16x8;
typedef __attribute__((ext_vector_type(4))) float f32x4;
typedef __attribute__((ext_vector_type(16))) float f32x16;

// scores are computed in exp2 domain: Q is pre-scaled by 0.125 * log2(e)
#define QSCALE 0.18033688011112042f
#define NEGBIG -3.0e38f

#define CVTPK(dst, a, b) \
    asm("v_cvt_pk_bf16_f32 %0, %1, %2" : "=v"(dst) : "v"(a), "v"(b))
#define PLSWAP(a, b) \
    asm("v_permlane32_swap_b32 %0, %1" : "+v"(a), "+v"(b))
#define GLOAD16(gp, lp)                                                        \
    __builtin_amdgcn_global_load_lds(                                          \
        (const __attribute__((address_space(1))) unsigned*)(gp),               \
        (__attribute__((address_space(3))) unsigned*)(lp), 16, 0, 0)
#define VMCNT0() asm volatile("s_waitcnt vmcnt(0)" ::: "memory")
#define VMCNT3() asm volatile("s_waitcnt vmcnt(3)" ::: "memory")
#define VMCNT6() asm volatile("s_waitcnt vmcnt(6)" ::: "memory")
#define SBAR() __builtin_amdgcn_s_barrier()
#define SCHED0() __builtin_amdgcn_sched_barrier(0)

__device__ __forceinline__ unsigned short bfround(float f) {
    union { float f; unsigned u; } v; v.f = f;
    unsigned u = v.u;
    u += 0x7fffu + ((u >> 16) & 1u);
    return (unsigned short)(u >> 16);
}

// ---------------------------------------------------------------------------
// Fragment-major global layouts for attention operands (16B chunk = 8 shorts;
// a wave's chunk load is 64 lanes x 16B fully coalesced).
// ---------------------------------------------------------------------------
__device__ __forceinline__ size_t qf_off(int s, int dk) {
    return ((size_t)(((s >> 5) * 4 + (dk >> 4)) * 64 + ((dk >> 3) & 1) * 32 + (s & 31)) << 3) + (dk & 7);
}
__device__ __forceinline__ size_t kf_off(int s, int dk) {
    return ((size_t)(((s >> 6) * 8 + ((s >> 5) & 1) * 4 + (dk >> 4)) * 64 + ((dk >> 3) & 1) * 32 + (s & 31)) << 3) + (dk & 7);
}
__device__ __forceinline__ size_t vf_off(int s, int dk) {
    return ((size_t)(((s >> 6) * 8 + (dk >> 5) * 4 + ((s >> 4) & 3)) * 64 + ((s >> 3) & 1) * 32 + (dk & 31)) << 3) + (s & 7);
}

// ---------------------------------------------------------------------------
// Kernel 1: transpose + convert the four 512x512 fp32 weights ([in][out]) into
// bf16 Wt[out][in].
// ---------------------------------------------------------------------------
__global__ __launch_bounds__(256) void wt_kernel(const float* __restrict__ W0,
                                                 const float* __restrict__ W1,
                                                 const float* __restrict__ W2,
                                                 const float* __restrict__ W3,
                                                 unsigned short* __restrict__ wt) {
    __shared__ float sh[64][65];
    const int z = blockIdx.z;
    const float* W = z == 0 ? W0 : z == 1 ? W1 : z == 2 ? W2 : W3;
    unsigned short* out = wt + (size_t)z * ND * ND;
    const int o0 = blockIdx.x * 64, i0 = blockIdx.y * 64;
    const int tx = threadIdx.x & 63;
    const int ty = threadIdx.x >> 6;  // 0..3
    #pragma unroll
    for (int rr = 0; rr < 16; ++rr) {
        const int row = ty * 16 + rr;  // local i
        sh[row][tx] = W[(size_t)(i0 + row) * ND + o0 + tx];
    }
    __syncthreads();
    #pragma unroll
    for (int rr = 0; rr < 16; ++rr) {
        const int row = ty * 16 + rr;  // local o
        out[(size_t)(o0 + row) * ND + i0 + tx] = bfround(sh[tx][row]);
    }
}

// ---------------------------------------------------------------------------
// Kernel 2: QKV projection GEMM, depth-2 COUNTED-vmcnt pipeline (T4).
// The R7 version drained vmcnt(0) at every phase end = m218's null "drain0"
// variant. Now: prologue stages tiles 0,1 (12 loads in flight); each phase
// waits vmcnt(6) (only tile t's 6 loads; t+1's fly through the barrier),
// computes t, barriers, stages t+2 into the freed buffer. vmcnt never 0 in
// the main loop; tail peeled (vmcnt(6) then vmcnt(0)).
// Tile 128x128, BK=32, 4 waves (2x2), wave-tile 64x64. A staged fp32 with
// 16B-unit XOR swizzle on the global source; bf16 convert at fragment read.
// ---------------------------------------------------------------------------
__global__ __launch_bounds__(256) void gemm_qkv(
    const float* __restrict__ A0, const float* __restrict__ A1, const float* __restrict__ A2,
    const unsigned short* __restrict__ wt,
    const float* __restrict__ b0, const float* __restrict__ b1, const float* __restrict__ b2,
    unsigned short* __restrict__ outb) {
    __shared__ float Asf[2][128 * 32];           // 2 x 16 KB
    __shared__ unsigned short Bs[2][128 * 32];   // 2 x 8 KB
    const int t = threadIdx.x;
    const int lane = t & 63, w = t >> 6;
    const int wr = w >> 1, wc = w & 1;
    const int lr = lane & 15, lg = lane >> 4;
    const int bid = blockIdx.x;               // 768 blocks
    const int u = (bid & 7) * 96 + (bid >> 3);
    const int xt = u & 3, yt = (u >> 2) & 63, z = u >> 8;
    const float* A = z == 0 ? A0 : z == 1 ? A1 : A2;
    const float* bias = z == 0 ? b0 : z == 1 ? b1 : b2;
    const unsigned short* Wt = wt + (size_t)z * ND * ND;
    unsigned short* outp = outb + (size_t)z * NB * NH * NS * NDK;
    const int m0 = yt * 128, n0 = xt * 128;

    // per-lane staging geometry (constant across ksteps)
    const int a_row = w * 32 + (lane >> 3);             // + j*8
    const int a_gc = ((lane & 7) ^ (lane >> 3)) << 2;   // swizzled fp32 col
    const int b_row = w * 32 + (lane >> 2);             // + j*16
    const int b_gc = (lane & 3) * 8;

    f32x4 acc[4][4];
    #pragma unroll
    for (int i = 0; i < 4; ++i)
        #pragma unroll
        for (int j = 0; j < 4; ++j) acc[i][j] = (f32x4){0.f, 0.f, 0.f, 0.f};

#define QKV_STAGE(p, kt) do {                                                  \
        const int _k0 = (kt) * 32;                                             \
        GLOAD16(A + (size_t)(m0 + a_row + 0)  * ND + _k0 + a_gc, &Asf[p][(w * 4 + 0) * 256]); \
        GLOAD16(A + (size_t)(m0 + a_row + 8)  * ND + _k0 + a_gc, &Asf[p][(w * 4 + 1) * 256]); \
        GLOAD16(A + (size_t)(m0 + a_row + 16) * ND + _k0 + a_gc, &Asf[p][(w * 4 + 2) * 256]); \
        GLOAD16(A + (size_t)(m0 + a_row + 24) * ND + _k0 + a_gc, &Asf[p][(w * 4 + 3) * 256]); \
        GLOAD16(Wt + (size_t)(n0 + b_row + 0)  * ND + _k0 + b_gc, &Bs[p][(w * 2 + 0) * 512]); \
        GLOAD16(Wt + (size_t)(n0 + b_row + 16) * ND + _k0 + b_gc, &Bs[p][(w * 2 + 1) * 512]); \
        SCHED0();                                                              \
    } while (0)

#define QKV_COMPUTE(p) do {                                                    \
        const float* _Ab = &Asf[p][0];                                         \
        const unsigned short* _Bb = &Bs[p][0];                                 \
        bf16x8 af[4], bfr[4];                                                  \
        _Pragma("unroll")                                                      \
        for (int mi = 0; mi < 4; ++mi) {                                       \
            const int r = wr * 64 + mi * 16 + lr;                              \
            const int u0 = (2 * lg) ^ (lr & 7);                                \
            const f32x4 x0 = *(const f32x4*)(_Ab + r * 32 + u0 * 4);           \
            const f32x4 x1 = *(const f32x4*)(_Ab + r * 32 + (u0 ^ 1) * 4);     \
            unsigned c0, c1, c2, c3;                                           \
            CVTPK(c0, x0[0], x0[1]); CVTPK(c1, x0[2], x0[3]);                  \
            CVTPK(c2, x1[0], x1[1]); CVTPK(c3, x1[2], x1[3]);                  \
            union { unsigned uu[4]; bf16x8 v; } cc;                            \
            cc.uu[0] = c0; cc.uu[1] = c1; cc.uu[2] = c2; cc.uu[3] = c3;        \
            af[mi] = cc.v;                                                     \
        }                                                                      \
        _Pragma("unroll")                                                      \
        for (int nj = 0; nj < 4; ++nj)                                         \
            bfr[nj] = *(const bf16x8*)(_Bb + (wc * 64 + nj * 16 + lr) * 32 + lg * 8); \
        __builtin_amdgcn_s_setprio(1);                                         \
        _Pragma("unroll")                                                      \
        for (int mi = 0; mi < 4; ++mi)                                         \
            _Pragma("unroll")                                                  \
            for (int nj = 0; nj < 4; ++nj)                                     \
                acc[mi][nj] = __builtin_amdgcn_mfma_f32_16x16x32_bf16(         \
                    af[mi], bfr[nj], acc[mi][nj], 0, 0, 0);                    \
        __builtin_amdgcn_s_setprio(0);                                         \
    } while (0)

    QKV_STAGE(0, 0);
    QKV_STAGE(1, 1);
    #pragma unroll 1
    for (int ii = 0; ii < 7; ++ii) {
        VMCNT6();               // tile 2ii ready; 2ii+1's 6 loads stay in flight
        SBAR();
        QKV_COMPUTE(0);
        SBAR();                 // all waves done reading buf0
        QKV_STAGE(0, 2 * ii + 2);
        VMCNT6();               // tile 2ii+1 ready; 2ii+2's stay in flight
        SBAR();
        QKV_COMPUTE(1);
        SBAR();
        QKV_STAGE(1, 2 * ii + 3);
    }
    // tail: tiles 14 (buf0), 15 (buf1)
    VMCNT6();
    SBAR();
    QKV_COMPUTE(0);
    VMCNT0();
    SBAR();
    QKV_COMPUTE(1);
#undef QKV_STAGE
#undef QKV_COMPUTE

    const float osc = z == 0 ? QSCALE : 1.0f;
    #pragma unroll
    for (int mi = 0; mi < 4; ++mi) {
        #pragma unroll
        for (int nj = 0; nj < 4; ++nj) {
            const int n = n0 + wc * 64 + nj * 16 + lr;
            const float bv = bias[n];
            #pragma unroll
            for (int r = 0; r < 4; ++r) {
                const int m = m0 + wr * 64 + mi * 16 + lg * 4 + r;
                const float val = (acc[mi][nj][r] + bv) * osc;
                const int bb = m >> 10, s = m & 1023;    // m = b*S + s
                const int hh = n >> 6, dk = n & 63;      // n = h*64 + dk
                const size_t off = z == 0 ? qf_off(s, dk)
                                 : z == 1 ? kf_off(s, dk)
                                          : vf_off(s, dk);
                outp[((size_t)(bb * NH + hh) << 16) + off] = bfround(val);
            }
        }
    }
}

// ---------------------------------------------------------------------------
// Kernel 4: output projection GEMM, same depth-2 counted pipeline (vmcnt(3)).
// Tile 128x64 (512 blocks), BK=32, 4 waves (2x2), wave-tile 64x32. fp32 out.
// ---------------------------------------------------------------------------
__global__ __launch_bounds__(256) void gemm_out(
    const unsigned short* __restrict__ Xb, const unsigned short* __restrict__ Wt,
    const float* __restrict__ bo, float* __restrict__ outp) {
    __shared__ unsigned short As2[2][128 * 32];   // 2 x 8 KB
    __shared__ unsigned short Bs2[2][64 * 32];    // 2 x 4 KB
    const int t = threadIdx.x;
    const int lane = t & 63, w = t >> 6;
    const int wr = w >> 1, wc = w & 1;
    const int lr = lane & 15, lg = lane >> 4;
    const int bid = blockIdx.x;               // 512 blocks
    const int u = (bid & 7) * 64 + (bid >> 3);
    const int xt = u & 7, yt = u >> 3;
    const int m0 = yt * 128, n0 = xt * 64;

    const int a_row = w * 32 + (lane >> 2);   // + j*16
    const int b_row = w * 16 + (lane >> 2);
    const int gc = (lane & 3) * 8;

    f32x4 acc[4][2];
    #pragma unroll
    for (int i = 0; i < 4; ++i)
        #pragma unroll
        for (int j = 0; j < 2; ++j) acc[i][j] = (f32x4){0.f, 0.f, 0.f, 0.f};

#define OUT_STAGE(p, kt) do {                                                  \
        const int _k0 = (kt) * 32;                                             \
        GLOAD16(Xb + (size_t)(m0 + a_row + 0)  * ND + _k0 + gc, &As2[p][(w * 2 + 0) * 512]); \
        GLOAD16(Xb + (size_t)(m0 + a_row + 16) * ND + _k0 + gc, &As2[p][(w * 2 + 1) * 512]); \
        GLOAD16(Wt + (size_t)(n0 + b_row) * ND + _k0 + gc, &Bs2[p][w * 512]);  \
        SCHED0();                                                              \
    } while (0)

#define OUT_COMPUTE(p) do {                                                    \
        const unsigned short* _Ab = &As2[p][0];                                \
        const unsigned short* _Bb = &Bs2[p][0];                                \
        bf16x8 af[4], bfr[2];                                                  \
        _Pragma("unroll")                                                      \
        for (int mi = 0; mi < 4; ++mi)                                         \
            af[mi] = *(const bf16x8*)(_Ab + (wr * 64 + mi * 16 + lr) * 32 + lg * 8); \
        _Pragma("unroll")                                                      \
        for (int nj = 0; nj < 2; ++nj)                                         \
            bfr[nj] = *(const bf16x8*)(_Bb + (wc * 32 + nj * 16 + lr) * 32 + lg * 8); \
        __builtin_amdgcn_s_setprio(1);                                         \
        _Pragma("unroll")                                                      \
        for (int mi = 0; mi < 4; ++mi)                                         \
            _Pragma("unroll")                                                  \
            for (int nj = 0; nj < 2; ++nj)                                     \
                acc[mi][nj] = __builtin_amdgcn_mfma_f32_16x16x32_bf16(         \
                    af[mi], bfr[nj], acc[mi][nj], 0, 0, 0);                    \
        __builtin_amdgcn_s_setprio(0);                                         \
    } while (0)

    OUT_STAGE(0, 0);
    OUT_STAGE(1, 1);
    #pragma unroll 1
    for (int ii = 0; ii < 7; ++ii) {
        VMCNT3();
        SBAR();
        OUT_COMPUTE(0);
        SBAR();
        OUT_STAGE(0, 2 * ii + 2);
        VMCNT3();
        SBAR();
        OUT_COMPUTE(1);
        SBAR();
        OUT_STAGE(1, 2 * ii + 3);
    }
    VMCNT3();
    SBAR();
    OUT_COMPUTE(0);
    VMCNT0();
    SBAR();
    OUT_COMPUTE(1);
#undef OUT_STAGE
#undef OUT_COMPUTE

    #pragma unroll
    for (int mi = 0; mi < 4; ++mi) {
        #pragma unroll
        for (int nj = 0; nj < 2; ++nj) {
            const int n = n0 + wc * 32 + nj * 16 + lr;
            const float bv = bo[n];
            #pragma unroll
            for (int r = 0; r < 4; ++r) {
                const int m = m0 + wr * 64 + mi * 16 + lg * 4 + r;
                outp[(size_t)m * ND + n] = acc[mi][nj][r] + bv;
            }
        }
    }
}

// ---------------------------------------------------------------------------
// Kernel 3: flash attention (unchanged from R5-R7 — fragment-major coalesced
// loads, swapped-operand 32x32 MFMA, in-register softmax, K double-buffer).
// ---------------------------------------------------------------------------
struct AttnState {
    f32x16 acc0, acc1;
    float m_st, l_st;
};

__device__ __forceinline__ void attn_step(const bf16x8 (&kf)[8], const bf16x8 (&vv)[8],
                                          const bf16x8 (&qf)[4], int mval,
                                          float* __restrict__ brow, int lane, int hi,
                                          AttnState& st) {
    brow[lane] = mval ? 0.f : NEGBIG;

    f32x16 sc0 = {}, sc1 = {};
    __builtin_amdgcn_s_setprio(1);
    sc0 = __builtin_amdgcn_mfma_f32_32x32x16_bf16(kf[0], qf[0], sc0, 0, 0, 0);
    sc1 = __builtin_amdgcn_mfma_f32_32x32x16_bf16(kf[4], qf[0], sc1, 0, 0, 0);
    sc0 = __builtin_amdgcn_mfma_f32_32x32x16_bf16(kf[1], qf[1], sc0, 0, 0, 0);
    sc1 = __builtin_amdgcn_mfma_f32_32x32x16_bf16(kf[5], qf[1], sc1, 0, 0, 0);
    sc0 = __builtin_amdgcn_mfma_f32_32x32x16_bf16(kf[2], qf[2], sc0, 0, 0, 0);
    sc1 = __builtin_amdgcn_mfma_f32_32x32x16_bf16(kf[6], qf[2], sc1, 0, 0, 0);
    sc0 = __builtin_amdgcn_mfma_f32_32x32x16_bf16(kf[3], qf[3], sc0, 0, 0, 0);
    sc1 = __builtin_amdgcn_mfma_f32_32x32x16_bf16(kf[7], qf[3], sc1, 0, 0, 0);
    __builtin_amdgcn_s_setprio(0);

    {
        const float* bl = brow + 4 * hi;
        #pragma unroll
        for (int mm = 0; mm < 4; ++mm) {
            const f32x4 bv0 = *(const f32x4*)(bl + 8 * mm);
            const f32x4 bv1 = *(const f32x4*)(bl + 32 + 8 * mm);
            #pragma unroll
            for (int c = 0; c < 4; ++c) {
                sc0[4 * mm + c] += bv0[c];
                sc1[4 * mm + c] += bv1[c];
            }
        }
    }

    float tv[16];
    #pragma unroll
    for (int r = 0; r < 16; ++r) tv[r] = fmaxf(sc0[r], sc1[r]);
    #pragma unroll
    for (int s = 8; s > 0; s >>= 1)
        #pragma unroll
        for (int r = 0; r < 16; ++r)
            if (r < s) tv[r] = fmaxf(tv[r], tv[r + s]);
    const float mx = fmaxf(tv[0], __shfl_xor(tv[0], 32));
    const float mn = fmaxf(st.m_st, mx);

    #pragma unroll
    for (int r = 0; r < 16; ++r) {
        sc0[r] = __builtin_amdgcn_exp2f(sc0[r] - mn);
        sc1[r] = __builtin_amdgcn_exp2f(sc1[r] - mn);
    }
    #pragma unroll
    for (int r = 0; r < 16; ++r) tv[r] = sc0[r] + sc1[r];
    #pragma unroll
    for (int s = 8; s > 0; s >>= 1)
        #pragma unroll
        for (int r = 0; r < 16; ++r)
            if (r < s) tv[r] += tv[r + s];
    const float rs = tv[0] + __shfl_xor(tv[0], 32);

    const bool ch = mn > st.m_st;
    if (__any(ch)) {
        const float f = __builtin_amdgcn_exp2f(st.m_st - mn);
        st.l_st = st.l_st * f + rs;
        st.m_st = mn;
        #pragma unroll
        for (int r = 0; r < 16; ++r) { st.acc0[r] *= f; st.acc1[r] *= f; }
    } else {
        st.l_st += rs;
    }

    union U8 { unsigned u[4]; bf16x8 v; };
    bf16x8 pA0, pA1, pB0, pB1;
    {
        unsigned w00, w01, w10, w11, w20, w21, w30, w31;
        CVTPK(w00, sc0[0], sc0[1]);  CVTPK(w01, sc0[2], sc0[3]);
        CVTPK(w10, sc0[4], sc0[5]);  CVTPK(w11, sc0[6], sc0[7]);
        CVTPK(w20, sc0[8], sc0[9]);  CVTPK(w21, sc0[10], sc0[11]);
        CVTPK(w30, sc0[12], sc0[13]); CVTPK(w31, sc0[14], sc0[15]);
        PLSWAP(w00, w10); PLSWAP(w01, w11);
        PLSWAP(w20, w30); PLSWAP(w21, w31);
        U8 f0; f0.u[0] = w00; f0.u[1] = w01; f0.u[2] = w10; f0.u[3] = w11;
        U8 f1; f1.u[0] = w20; f1.u[1] = w21; f1.u[2] = w30; f1.u[3] = w31;
        pA0 = f0.v; pA1 = f1.v;
    }
    {
        unsigned w00, w01, w10, w11, w20, w21, w30, w31;
        CVTPK(w00, sc1[0], sc1[1]);  CVTPK(w01, sc1[2], sc1[3]);
        CVTPK(w10, sc1[4], sc1[5]);  CVTPK(w11, sc1[6], sc1[7]);
        CVTPK(w20, sc1[8], sc1[9]);  CVTPK(w21, sc1[10], sc1[11]);
        CVTPK(w30, sc1[12], sc1[13]); CVTPK(w31, sc1[14], sc1[15]);
        PLSWAP(w00, w10); PLSWAP(w01, w11);
        PLSWAP(w20, w30); PLSWAP(w21, w31);
        U8 f0; f0.u[0] = w00; f0.u[1] = w01; f0.u[2] = w10; f0.u[3] = w11;
        U8 f1; f1.u[0] = w20; f1.u[1] = w21; f1.u[2] = w30; f1.u[3] = w31;
        pB0 = f0.v; pB1 = f1.v;
    }

    __builtin_amdgcn_s_setprio(1);
    st.acc0 = __builtin_amdgcn_mfma_f32_32x32x16_bf16(vv[0], pA0, st.acc0, 0, 0, 0);
    st.acc1 = __builtin_amdgcn_mfma_f32_32x32x16_bf16(vv[4], pA0, st.acc1, 0, 0, 0);
    st.acc0 = __builtin_amdgcn_mfma_f32_32x32x16_bf16(vv[1], pA1, st.acc0, 0, 0, 0);
    st.acc1 = __builtin_amdgcn_mfma_f32_32x32x16_bf16(vv[5], pA1, st.acc1, 0, 0, 0);
    st.acc0 = __builtin_amdgcn_mfma_f32_32x32x16_bf16(vv[2], pB0, st.acc0, 0, 0, 0);
    st.acc1 = __builtin_amdgcn_mfma_f32_32x32x16_bf16(vv[6], pB0, st.acc1, 0, 0, 0);
    st.acc0 = __builtin_amdgcn_mfma_f32_32x32x16_bf16(vv[3], pB1, st.acc0, 0, 0, 0);
    st.acc1 = __builtin_amdgcn_mfma_f32_32x32x16_bf16(vv[7], pB1, st.acc1, 0, 0, 0);
    __builtin_amdgcn_s_setprio(0);
}

__global__ __launch_bounds__(256, 2) void attn_kernel(const unsigned short* __restrict__ QF,
                                                      const unsigned short* __restrict__ KF,
                                                      const unsigned short* __restrict__ VF,
                                                      const int* __restrict__ mask,
                                                      unsigned short* __restrict__ Xb) {
    __shared__ float bias_lds[4][64];
    const int t = threadIdx.x;
    const int lane = t & 63, w = t >> 6;
    const int q32 = lane & 31, hi = lane >> 5;
    const int bid = blockIdx.x;                  // 512 blocks
    const int u = (bid & 7) * 64 + (bid >> 3);
    const int bh = u >> 3, xq = u & 7;
    const int b = bh >> 3, h = bh & 7;
    const int q = xq * 128 + w * 32 + q32;
    const unsigned short* QFh = QF + ((size_t)bh << 16);
    const unsigned short* KFh = KF + ((size_t)bh << 16);
    const unsigned short* VFh = VF + ((size_t)bh << 16);
    const int* mk = mask + b * NS;
    float* brow = &bias_lds[w][0];

    bf16x8 qf[4];
    {
        const unsigned short* Qp = QFh + (size_t)(xq * 16 + w * 4) * 512 + lane * 8;
        qf[0] = *(const bf16x8*)(Qp + 0 * 512);
        qf[1] = *(const bf16x8*)(Qp + 1 * 512);
        qf[2] = *(const bf16x8*)(Qp + 2 * 512);
        qf[3] = *(const bf16x8*)(Qp + 3 * 512);
    }

    AttnState st;
    st.acc0 = (f32x16){}; st.acc1 = (f32x16){};
    st.m_st = -1.0e30f; st.l_st = 0.f;

    bf16x8 kA[8], kB[8], vv[8];

#define LOADK(dst, itx) do {                                                   \
        const unsigned short* _p = KFh + (size_t)(itx) * 4096 + lane * 8;      \
        dst[0] = *(const bf16x8*)(_p + 0 * 512);                               \
        dst[1] = *(const bf16x8*)(_p + 1 * 512);                               \
        dst[2] = *(const bf16x8*)(_p + 2 * 512);                               \
        dst[3] = *(const bf16x8*)(_p + 3 * 512);                               \
        dst[4] = *(const bf16x8*)(_p + 4 * 512);                               \
        dst[5] = *(const bf16x8*)(_p + 5 * 512);                               \
        dst[6] = *(const bf16x8*)(_p + 6 * 512);                               \
        dst[7] = *(const bf16x8*)(_p + 7 * 512);                               \
    } while (0)

#define LOADV(dst, itx) do {                                                   \
        const unsigned short* _p = VFh + (size_t)(itx) * 4096 + lane * 8;      \
        dst[0] = *(const bf16x8*)(_p + 0 * 512);                               \
        dst[1] = *(const bf16x8*)(_p + 1 * 512);                               \
        dst[2] = *(const bf16x8*)(_p + 2 * 512);                               \
        dst[3] = *(const bf16x8*)(_p + 3 * 512);                               \
        dst[4] = *(const bf16x8*)(_p + 4 * 512);                               \
        dst[5] = *(const bf16x8*)(_p + 5 * 512);                               \
        dst[6] = *(const bf16x8*)(_p + 6 * 512);                               \
        dst[7] = *(const bf16x8*)(_p + 7 * 512);                               \
    } while (0)

    LOADK(kA, 0);
    #pragma unroll 1
    for (int ii = 0; ii < 8; ++ii) {
        const int itE = ii * 2, itO = itE + 1;
        const int mE = mk[itE * 64 + lane];
        LOADV(vv, itE);
        LOADK(kB, itO);
        __builtin_amdgcn_sched_barrier(0);
        attn_step(kA, vv, qf, mE, brow, lane, hi, st);
        const int mO = mk[itO * 64 + lane];
        const int itN = itO + 1 > 15 ? 15 : itO + 1;
        LOADV(vv, itO);
        LOADK(kA, itN);
        __builtin_amdgcn_sched_barrier(0);
        attn_step(kB, vv, qf, mO, brow, lane, hi, st);
    }
#undef LOADK
#undef LOADV

    const float inv = st.l_st > 0.f ? 1.f / st.l_st : 0.f;
    unsigned short* Xp = Xb + (size_t)(b * NS + q) * ND + h * 64 + 4 * hi;
    #pragma unroll
    for (int mm = 0; mm < 4; ++mm) {
        unsigned w0, w1;
        CVTPK(w0, st.acc0[4 * mm] * inv, st.acc0[4 * mm + 1] * inv);
        CVTPK(w1, st.acc0[4 * mm + 2] * inv, st.acc0[4 * mm + 3] * inv);
        uint2 pv; pv.x = w0; pv.y = w1;
        *(uint2*)(Xp + 8 * mm) = pv;
        CVTPK(w0, st.acc1[4 * mm] * inv, st.acc1[4 * mm + 1] * inv);
        CVTPK(w1, st.acc1[4 * mm + 2] * inv, st.acc1[4 * mm + 3] * inv);
        pv.x = w0; pv.y = w1;
        *(uint2*)(Xp + 32 + 8 * mm) = pv;
    }
}

// ---------------------------------------------------------------------------
// Host launcher. Workspace (bf16 elements): wt(4*512*512), QF, KF, VF, Xb.
// ---------------------------------------------------------------------------
extern "C" void kernel_launch(void* const* d_in, const int* in_sizes, int n_in,
                              void* d_out, int out_size, void* d_ws, size_t ws_size,
                              hipStream_t stream) {
    const float* query = (const float*)d_in[0];
    const float* key   = (const float*)d_in[1];
    const float* value = (const float*)d_in[2];
    const int*   mask  = (const int*)d_in[3];
    const float* Wq = (const float*)d_in[4];
    const float* bq = (const float*)d_in[5];
    const float* Wk = (const float*)d_in[6];
    const float* bk = (const float*)d_in[7];
    const float* Wv = (const float*)d_in[8];
    const float* bv = (const float*)d_in[9];
    const float* Wo = (const float*)d_in[10];
    const float* bo = (const float*)d_in[11];

    const size_t HEADSZ = (size_t)NB * NH * NS * NDK;  // 4194304
    unsigned short* wt = (unsigned short*)d_ws;
    unsigned short* QFb = wt + (size_t)4 * ND * ND;
    unsigned short* KFb = QFb + HEADSZ;
    unsigned short* VFb = KFb + HEADSZ;
    unsigned short* Xb  = VFb + HEADSZ;

    // 1. weights -> bf16, transposed
    wt_kernel<<<dim3(8, 8, 4), 256, 0, stream>>>(Wq, Wk, Wv, Wo, wt);

    // 2. QKV projections into fragment-major layouts (z = q/k/v)
    gemm_qkv<<<768, 256, 0, stream>>>(query, key, value, wt, bq, bk, bv, QFb);

    // 3. attention (512 blocks, 4 waves each, no barriers)
    attn_kernel<<<512, 256, 0, stream>>>(QFb, KFb, VFb, mask, Xb);

    // 4. output projection (fp32 out)
    gemm_out<<<512, 256, 0, stream>>>(Xb, wt + (size_t)3 * ND * ND, bo, (float*)d_out);
}

// Round 9
// 81.990 us; speedup vs baseline: 1.0102x; 1.0011x over previous
//
#include <hip/hip_runtime.h>
#include <hip/hip_bf16.h>

// Shapes (fixed by the reference)
#define NB 8
#define NS 1024
#define ND 512
#define NH 8
#define NDK 64

typedef __attribute__((ext_vector_type(8))) short bf16x8;
typedef __attribute__((ext_vector_type(4))) float f32x4;
typedef __attribute__((ext_vector_type(16))) float f32x16;

// scores are computed in exp2 domain: Q is pre-scaled by 0.125 * log2(e)
#define QSCALE 0.18033688011112042f
#define NEGBIG -3.0e38f

#define CVTPK(dst, a, b) \
    asm("v_cvt_pk_bf16_f32 %0, %1, %2" : "=v"(dst) : "v"(a), "v"(b))
#define PLSWAP(a, b) \
    asm("v_permlane32_swap_b32 %0, %1" : "+v"(a), "+v"(b))

__device__ __forceinline__ unsigned short bfround(float f) {
    union { float f; unsigned u; } v; v.f = f;
    unsigned u = v.u;
    u += 0x7fffu + ((u >> 16) & 1u);
    return (unsigned short)(u >> 16);
}

// ---------------------------------------------------------------------------
// Fragment-major global layouts for attention operands (16B chunk = 8 shorts;
// a wave's chunk load is 64 lanes x 16B fully coalesced).
// ---------------------------------------------------------------------------
__device__ __forceinline__ size_t qf_off(int s, int dk) {
    return ((size_t)(((s >> 5) * 4 + (dk >> 4)) * 64 + ((dk >> 3) & 1) * 32 + (s & 31)) << 3) + (dk & 7);
}
__device__ __forceinline__ size_t kf_off(int s, int dk) {
    return ((size_t)(((s >> 6) * 8 + ((s >> 5) & 1) * 4 + (dk >> 4)) * 64 + ((dk >> 3) & 1) * 32 + (s & 31)) << 3) + (dk & 7);
}
__device__ __forceinline__ size_t vf_off(int s, int dk) {
    return ((size_t)(((s >> 6) * 8 + (dk >> 5) * 4 + ((s >> 4) & 3)) * 64 + ((s >> 3) & 1) * 32 + (dk & 31)) << 3) + (s & 7);
}

// ---------------------------------------------------------------------------
// Kernel 1: transpose + convert the four 512x512 fp32 weights ([in][out]) into
// bf16 Wt[out][in].
// ---------------------------------------------------------------------------
__global__ __launch_bounds__(256) void wt_kernel(const float* __restrict__ W0,
                                                 const float* __restrict__ W1,
                                                 const float* __restrict__ W2,
                                                 const float* __restrict__ W3,
                                                 unsigned short* __restrict__ wt) {
    __shared__ float sh[64][65];
    const int z = blockIdx.z;
    const float* W = z == 0 ? W0 : z == 1 ? W1 : z == 2 ? W2 : W3;
    unsigned short* out = wt + (size_t)z * ND * ND;
    const int o0 = blockIdx.x * 64, i0 = blockIdx.y * 64;
    const int tx = threadIdx.x & 63;
    const int ty = threadIdx.x >> 6;  // 0..3
    #pragma unroll
    for (int rr = 0; rr < 16; ++rr) {
        const int row = ty * 16 + rr;  // local i
        sh[row][tx] = W[(size_t)(i0 + row) * ND + o0 + tx];
    }
    __syncthreads();
    #pragma unroll
    for (int rr = 0; rr < 16; ++rr) {
        const int row = ty * 16 + rr;  // local o
        out[(size_t)(o0 + row) * ND + i0 + tx] = bfround(sh[tx][row]);
    }
}

// ---------------------------------------------------------------------------
// Kernel 2: QKV projection GEMM, reg-staged all-bf16 pad-40 LDS.
// The R5-R8 variants were invariant at ~44us across four staging schedules:
// the real costs were (a) 8-way bank conflicts on linear [128][32] bf16 reads
// (64B row stride = 16 banks), (b) 16 cvt_pk between ds_read and MFMA every
// phase, (c) 48KB fp32 LDS capping residency at 2 blocks/CU (no cross-block
// TLP to hide the barrier drain — the m114 mechanism).
// Now: global->VGPR loads (fp32 A cvt'd at STAGING time), ds_write into
// [128][40] bf16 (80B stride: 2-way read conflicts = free, 16B-aligned b128
// reads), 40KB LDS -> 4 blocks/CU, one barrier per phase, next-tile loads in
// registers flying under compute.
// Tile 128x128, BK=32, 4 waves (2x2), wave-tile 64x64.
// ---------------------------------------------------------------------------
__global__ __launch_bounds__(256) void gemm_qkv(
    const float* __restrict__ A0, const float* __restrict__ A1, const float* __restrict__ A2,
    const unsigned short* __restrict__ wt,
    const float* __restrict__ b0, const float* __restrict__ b1, const float* __restrict__ b2,
    unsigned short* __restrict__ outb) {
    __shared__ unsigned short Als[2][128 * 40];   // 2 x 10240 B
    __shared__ unsigned short Bls[2][128 * 40];   // 2 x 10240 B
    const int t = threadIdx.x;
    const int lane = t & 63, w = t >> 6;
    const int wr = w >> 1, wc = w & 1;
    const int lr = lane & 15, lg = lane >> 4;
    const int bid = blockIdx.x;               // 768 blocks
    const int u = (bid & 7) * 96 + (bid >> 3);
    const int xt = u & 3, yt = (u >> 2) & 63, z = u >> 8;
    const float* A = z == 0 ? A0 : z == 1 ? A1 : A2;
    const float* bias = z == 0 ? b0 : z == 1 ? b1 : b2;
    const unsigned short* Wt = wt + (size_t)z * ND * ND;
    unsigned short* outp = outb + (size_t)z * NB * NH * NS * NDK;
    const int m0 = yt * 128, n0 = xt * 128;

    // staging geometry: A per lane 4x f32x4 (rows a_row+8j, fp32 col a_col);
    // B per lane 2x bf16x8 (rows b_row+16j, col b_col)
    const int a_row = w * 32 + (lane >> 3);
    const int a_col = (lane & 7) * 4;
    const int b_row = w * 32 + (lane >> 2);
    const int b_col = (lane & 3) * 8;

    f32x4 acc[4][4];
    #pragma unroll
    for (int i = 0; i < 4; ++i)
        #pragma unroll
        for (int j = 0; j < 4; ++j) acc[i][j] = (f32x4){0.f, 0.f, 0.f, 0.f};

    f32x4 ra[4];
    bf16x8 rbv[2];

#define QKV_LOAD(kt) do {                                                      \
        const int _k0 = (kt) * 32;                                             \
        ra[0] = *(const f32x4*)(A + (size_t)(m0 + a_row + 0)  * ND + _k0 + a_col); \
        ra[1] = *(const f32x4*)(A + (size_t)(m0 + a_row + 8)  * ND + _k0 + a_col); \
        ra[2] = *(const f32x4*)(A + (size_t)(m0 + a_row + 16) * ND + _k0 + a_col); \
        ra[3] = *(const f32x4*)(A + (size_t)(m0 + a_row + 24) * ND + _k0 + a_col); \
        rbv[0] = *(const bf16x8*)(Wt + (size_t)(n0 + b_row + 0)  * ND + _k0 + b_col); \
        rbv[1] = *(const bf16x8*)(Wt + (size_t)(n0 + b_row + 16) * ND + _k0 + b_col); \
    } while (0)

#define QKV_WRITE(p) do {                                                      \
        _Pragma("unroll")                                                      \
        for (int j = 0; j < 4; ++j) {                                          \
            unsigned c0, c1;                                                   \
            CVTPK(c0, ra[j][0], ra[j][1]);                                     \
            CVTPK(c1, ra[j][2], ra[j][3]);                                     \
            uint2 pv; pv.x = c0; pv.y = c1;                                    \
            *(uint2*)(&Als[p][(a_row + j * 8) * 40 + a_col]) = pv;             \
        }                                                                      \
        _Pragma("unroll")                                                      \
        for (int j = 0; j < 2; ++j) {                                          \
            union { bf16x8 v; uint2 h[2]; } ub; ub.v = rbv[j];                 \
            *(uint2*)(&Bls[p][(b_row + j * 16) * 40 + b_col]) = ub.h[0];       \
            *(uint2*)(&Bls[p][(b_row + j * 16) * 40 + b_col + 4]) = ub.h[1];   \
        }                                                                      \
    } while (0)

#define QKV_COMPUTE(p) do {                                                    \
        bf16x8 af[4], bfr[4];                                                  \
        _Pragma("unroll")                                                      \
        for (int mi = 0; mi < 4; ++mi)                                         \
            af[mi] = *(const bf16x8*)(&Als[p][(wr * 64 + mi * 16 + lr) * 40 + lg * 8]); \
        _Pragma("unroll")                                                      \
        for (int nj = 0; nj < 4; ++nj)                                         \
            bfr[nj] = *(const bf16x8*)(&Bls[p][(wc * 64 + nj * 16 + lr) * 40 + lg * 8]); \
        __builtin_amdgcn_s_setprio(1);                                         \
        _Pragma("unroll")                                                      \
        for (int mi = 0; mi < 4; ++mi)                                         \
            _Pragma("unroll")                                                  \
            for (int nj = 0; nj < 4; ++nj)                                     \
                acc[mi][nj] = __builtin_amdgcn_mfma_f32_16x16x32_bf16(         \
                    af[mi], bfr[nj], acc[mi][nj], 0, 0, 0);                    \
        __builtin_amdgcn_s_setprio(0);                                         \
    } while (0)

    QKV_LOAD(0);
    QKV_WRITE(0);
    QKV_LOAD(1);
    __syncthreads();
    #pragma unroll 1
    for (int kt = 0; kt < 15; ++kt) {
        QKV_COMPUTE(kt & 1);
        QKV_WRITE((kt + 1) & 1);    // regs for tile kt+1 (loads flew under compute)
        if (kt < 14) QKV_LOAD(kt + 2);
        __syncthreads();
    }
    QKV_COMPUTE(1);
#undef QKV_LOAD
#undef QKV_WRITE
#undef QKV_COMPUTE

    const float osc = z == 0 ? QSCALE : 1.0f;
    #pragma unroll
    for (int mi = 0; mi < 4; ++mi) {
        #pragma unroll
        for (int nj = 0; nj < 4; ++nj) {
            const int n = n0 + wc * 64 + nj * 16 + lr;
            const float bv = bias[n];
            #pragma unroll
            for (int r = 0; r < 4; ++r) {
                const int m = m0 + wr * 64 + mi * 16 + lg * 4 + r;
                const float val = (acc[mi][nj][r] + bv) * osc;
                const int bb = m >> 10, s = m & 1023;    // m = b*S + s
                const int hh = n >> 6, dk = n & 63;      // n = h*64 + dk
                const size_t off = z == 0 ? qf_off(s, dk)
                                 : z == 1 ? kf_off(s, dk)
                                          : vf_off(s, dk);
                outp[((size_t)(bb * NH + hh) << 16) + off] = bfround(val);
            }
        }
    }
}

// ---------------------------------------------------------------------------
// Kernel 4: output projection GEMM, same reg-staged pad-40 structure.
// Tile 128x64 (512 blocks), BK=32, 4 waves (2x2), wave-tile 64x32. fp32 out.
// ---------------------------------------------------------------------------
__global__ __launch_bounds__(256) void gemm_out(
    const unsigned short* __restrict__ Xb, const unsigned short* __restrict__ Wt,
    const float* __restrict__ bo, float* __restrict__ outp) {
    __shared__ unsigned short Ao[2][128 * 40];   // 2 x 10240 B
    __shared__ unsigned short Bo[2][64 * 40];    // 2 x 5120 B
    const int t = threadIdx.x;
    const int lane = t & 63, w = t >> 6;
    const int wr = w >> 1, wc = w & 1;
    const int lr = lane & 15, lg = lane >> 4;
    const int bid = blockIdx.x;               // 512 blocks
    const int u = (bid & 7) * 64 + (bid >> 3);
    const int xt = u & 7, yt = u >> 3;
    const int m0 = yt * 128, n0 = xt * 64;

    const int a_row = w * 32 + (lane >> 2);   // + j*16
    const int b_row = w * 16 + (lane >> 2);
    const int gc = (lane & 3) * 8;

    f32x4 acc[4][2];
    #pragma unroll
    for (int i = 0; i < 4; ++i)
        #pragma unroll
        for (int j = 0; j < 2; ++j) acc[i][j] = (f32x4){0.f, 0.f, 0.f, 0.f};

    bf16x8 raa[2], rbb;

#define OUT_LOAD(kt) do {                                                      \
        const int _k0 = (kt) * 32;                                             \
        raa[0] = *(const bf16x8*)(Xb + (size_t)(m0 + a_row + 0)  * ND + _k0 + gc); \
        raa[1] = *(const bf16x8*)(Xb + (size_t)(m0 + a_row + 16) * ND + _k0 + gc); \
        rbb    = *(const bf16x8*)(Wt + (size_t)(n0 + b_row) * ND + _k0 + gc);  \
    } while (0)

#define OUT_WRITE(p) do {                                                      \
        _Pragma("unroll")                                                      \
        for (int j = 0; j < 2; ++j) {                                          \
            union { bf16x8 v; uint2 h[2]; } ua; ua.v = raa[j];                 \
            *(uint2*)(&Ao[p][(a_row + j * 16) * 40 + gc]) = ua.h[0];           \
            *(uint2*)(&Ao[p][(a_row + j * 16) * 40 + gc + 4]) = ua.h[1];       \
        }                                                                      \
        {                                                                      \
            union { bf16x8 v; uint2 h[2]; } ub; ub.v = rbb;                    \
            *(uint2*)(&Bo[p][b_row * 40 + gc]) = ub.h[0];                      \
            *(uint2*)(&Bo[p][b_row * 40 + gc + 4]) = ub.h[1];                  \
        }                                                                      \
    } while (0)

#define OUT_COMPUTE(p) do {                                                    \
        bf16x8 af[4], bfr[2];                                                  \
        _Pragma("unroll")                                                      \
        for (int mi = 0; mi < 4; ++mi)                                         \
            af[mi] = *(const bf16x8*)(&Ao[p][(wr * 64 + mi * 16 + lr) * 40 + lg * 8]); \
        _Pragma("unroll")                                                      \
        for (int nj = 0; nj < 2; ++nj)                                         \
            bfr[nj] = *(const bf16x8*)(&Bo[p][(wc * 32 + nj * 16 + lr) * 40 + lg * 8]); \
        __builtin_amdgcn_s_setprio(1);                                         \
        _Pragma("unroll")                                                      \
        for (int mi = 0; mi < 4; ++mi)                                         \
            _Pragma("unroll")                                                  \
            for (int nj = 0; nj < 2; ++nj)                                     \
                acc[mi][nj] = __builtin_amdgcn_mfma_f32_16x16x32_bf16(         \
                    af[mi], bfr[nj], acc[mi][nj], 0, 0, 0);                    \
        __builtin_amdgcn_s_setprio(0);                                         \
    } while (0)

    OUT_LOAD(0);
    OUT_WRITE(0);
    OUT_LOAD(1);
    __syncthreads();
    #pragma unroll 1
    for (int kt = 0; kt < 15; ++kt) {
        OUT_COMPUTE(kt & 1);
        OUT_WRITE((kt + 1) & 1);
        if (kt < 14) OUT_LOAD(kt + 2);
        __syncthreads();
    }
    OUT_COMPUTE(1);
#undef OUT_LOAD
#undef OUT_WRITE
#undef OUT_COMPUTE

    #pragma unroll
    for (int mi = 0; mi < 4; ++mi) {
        #pragma unroll
        for (int nj = 0; nj < 2; ++nj) {
            const int n = n0 + wc * 32 + nj * 16 + lr;
            const float bv = bo[n];
            #pragma unroll
            for (int r = 0; r < 4; ++r) {
                const int m = m0 + wr * 64 + mi * 16 + lg * 4 + r;
                outp[(size_t)m * ND + n] = acc[mi][nj][r] + bv;
            }
        }
    }
}

// ---------------------------------------------------------------------------
// Kernel 3: flash attention (unchanged from R5-R8 — fragment-major coalesced
// loads, swapped-operand 32x32 MFMA, in-register softmax, K double-buffer).
// ---------------------------------------------------------------------------
struct AttnState {
    f32x16 acc0, acc1;
    float m_st, l_st;
};

__device__ __forceinline__ void attn_step(const bf16x8 (&kf)[8], const bf16x8 (&vv)[8],
                                          const bf16x8 (&qf)[4], int mval,
                                          float* __restrict__ brow, int lane, int hi,
                                          AttnState& st) {
    brow[lane] = mval ? 0.f : NEGBIG;

    f32x16 sc0 = {}, sc1 = {};
    __builtin_amdgcn_s_setprio(1);
    sc0 = __builtin_amdgcn_mfma_f32_32x32x16_bf16(kf[0], qf[0], sc0, 0, 0, 0);
    sc1 = __builtin_amdgcn_mfma_f32_32x32x16_bf16(kf[4], qf[0], sc1, 0, 0, 0);
    sc0 = __builtin_amdgcn_mfma_f32_32x32x16_bf16(kf[1], qf[1], sc0, 0, 0, 0);
    sc1 = __builtin_amdgcn_mfma_f32_32x32x16_bf16(kf[5], qf[1], sc1, 0, 0, 0);
    sc0 = __builtin_amdgcn_mfma_f32_32x32x16_bf16(kf[2], qf[2], sc0, 0, 0, 0);
    sc1 = __builtin_amdgcn_mfma_f32_32x32x16_bf16(kf[6], qf[2], sc1, 0, 0, 0);
    sc0 = __builtin_amdgcn_mfma_f32_32x32x16_bf16(kf[3], qf[3], sc0, 0, 0, 0);
    sc1 = __builtin_amdgcn_mfma_f32_32x32x16_bf16(kf[7], qf[3], sc1, 0, 0, 0);
    __builtin_amdgcn_s_setprio(0);

    {
        const float* bl = brow + 4 * hi;
        #pragma unroll
        for (int mm = 0; mm < 4; ++mm) {
            const f32x4 bv0 = *(const f32x4*)(bl + 8 * mm);
            const f32x4 bv1 = *(const f32x4*)(bl + 32 + 8 * mm);
            #pragma unroll
            for (int c = 0; c < 4; ++c) {
                sc0[4 * mm + c] += bv0[c];
                sc1[4 * mm + c] += bv1[c];
            }
        }
    }

    float tv[16];
    #pragma unroll
    for (int r = 0; r < 16; ++r) tv[r] = fmaxf(sc0[r], sc1[r]);
    #pragma unroll
    for (int s = 8; s > 0; s >>= 1)
        #pragma unroll
        for (int r = 0; r < 16; ++r)
            if (r < s) tv[r] = fmaxf(tv[r], tv[r + s]);
    const float mx = fmaxf(tv[0], __shfl_xor(tv[0], 32));
    const float mn = fmaxf(st.m_st, mx);

    #pragma unroll
    for (int r = 0; r < 16; ++r) {
        sc0[r] = __builtin_amdgcn_exp2f(sc0[r] - mn);
        sc1[r] = __builtin_amdgcn_exp2f(sc1[r] - mn);
    }
    #pragma unroll
    for (int r = 0; r < 16; ++r) tv[r] = sc0[r] + sc1[r];
    #pragma unroll
    for (int s = 8; s > 0; s >>= 1)
        #pragma unroll
        for (int r = 0; r < 16; ++r)
            if (r < s) tv[r] += tv[r + s];
    const float rs = tv[0] + __shfl_xor(tv[0], 32);

    const bool ch = mn > st.m_st;
    if (__any(ch)) {
        const float f = __builtin_amdgcn_exp2f(st.m_st - mn);
        st.l_st = st.l_st * f + rs;
        st.m_st = mn;
        #pragma unroll
        for (int r = 0; r < 16; ++r) { st.acc0[r] *= f; st.acc1[r] *= f; }
    } else {
        st.l_st += rs;
    }

    union U8 { unsigned u[4]; bf16x8 v; };
    bf16x8 pA0, pA1, pB0, pB1;
    {
        unsigned w00, w01, w10, w11, w20, w21, w30, w31;
        CVTPK(w00, sc0[0], sc0[1]);  CVTPK(w01, sc0[2], sc0[3]);
        CVTPK(w10, sc0[4], sc0[5]);  CVTPK(w11, sc0[6], sc0[7]);
        CVTPK(w20, sc0[8], sc0[9]);  CVTPK(w21, sc0[10], sc0[11]);
        CVTPK(w30, sc0[12], sc0[13]); CVTPK(w31, sc0[14], sc0[15]);
        PLSWAP(w00, w10); PLSWAP(w01, w11);
        PLSWAP(w20, w30); PLSWAP(w21, w31);
        U8 f0; f0.u[0] = w00; f0.u[1] = w01; f0.u[2] = w10; f0.u[3] = w11;
        U8 f1; f1.u[0] = w20; f1.u[1] = w21; f1.u[2] = w30; f1.u[3] = w31;
        pA0 = f0.v; pA1 = f1.v;
    }
    {
        unsigned w00, w01, w10, w11, w20, w21, w30, w31;
        CVTPK(w00, sc1[0], sc1[1]);  CVTPK(w01, sc1[2], sc1[3]);
        CVTPK(w10, sc1[4], sc1[5]);  CVTPK(w11, sc1[6], sc1[7]);
        CVTPK(w20, sc1[8], sc1[9]);  CVTPK(w21, sc1[10], sc1[11]);
        CVTPK(w30, sc1[12], sc1[13]); CVTPK(w31, sc1[14], sc1[15]);
        PLSWAP(w00, w10); PLSWAP(w01, w11);
        PLSWAP(w20, w30); PLSWAP(w21, w31);
        U8 f0; f0.u[0] = w00; f0.u[1] = w01; f0.u[2] = w10; f0.u[3] = w11;
        U8 f1; f1.u[0] = w20; f1.u[1] = w21; f1.u[2] = w30; f1.u[3] = w31;
        pB0 = f0.v; pB1 = f1.v;
    }

    __builtin_amdgcn_s_setprio(1);
    st.acc0 = __builtin_amdgcn_mfma_f32_32x32x16_bf16(vv[0], pA0, st.acc0, 0, 0, 0);
    st.acc1 = __builtin_amdgcn_mfma_f32_32x32x16_bf16(vv[4], pA0, st.acc1, 0, 0, 0);
    st.acc0 = __builtin_amdgcn_mfma_f32_32x32x16_bf16(vv[1], pA1, st.acc0, 0, 0, 0);
    st.acc1 = __builtin_amdgcn_mfma_f32_32x32x16_bf16(vv[5], pA1, st.acc1, 0, 0, 0);
    st.acc0 = __builtin_amdgcn_mfma_f32_32x32x16_bf16(vv[2], pB0, st.acc0, 0, 0, 0);
    st.acc1 = __builtin_amdgcn_mfma_f32_32x32x16_bf16(vv[6], pB0, st.acc1, 0, 0, 0);
    st.acc0 = __builtin_amdgcn_mfma_f32_32x32x16_bf16(vv[3], pB1, st.acc0, 0, 0, 0);
    st.acc1 = __builtin_amdgcn_mfma_f32_32x32x16_bf16(vv[7], pB1, st.acc1, 0, 0, 0);
    __builtin_amdgcn_s_setprio(0);
}

__global__ __launch_bounds__(256, 2) void attn_kernel(const unsigned short* __restrict__ QF,
                                                      const unsigned short* __restrict__ KF,
                                                      const unsigned short* __restrict__ VF,
                                                      const int* __restrict__ mask,
                                                      unsigned short* __restrict__ Xb) {
    __shared__ float bias_lds[4][64];
    const int t = threadIdx.x;
    const int lane = t & 63, w = t >> 6;
    const int q32 = lane & 31, hi = lane >> 5;
    const int bid = blockIdx.x;                  // 512 blocks
    const int u = (bid & 7) * 64 + (bid >> 3);
    const int bh = u >> 3, xq = u & 7;
    const int b = bh >> 3, h = bh & 7;
    const int q = xq * 128 + w * 32 + q32;
    const unsigned short* QFh = QF + ((size_t)bh << 16);
    const unsigned short* KFh = KF + ((size_t)bh << 16);
    const unsigned short* VFh = VF + ((size_t)bh << 16);
    const int* mk = mask + b * NS;
    float* brow = &bias_lds[w][0];

    bf16x8 qf[4];
    {
        const unsigned short* Qp = QFh + (size_t)(xq * 16 + w * 4) * 512 + lane * 8;
        qf[0] = *(const bf16x8*)(Qp + 0 * 512);
        qf[1] = *(const bf16x8*)(Qp + 1 * 512);
        qf[2] = *(const bf16x8*)(Qp + 2 * 512);
        qf[3] = *(const bf16x8*)(Qp + 3 * 512);
    }

    AttnState st;
    st.acc0 = (f32x16){}; st.acc1 = (f32x16){};
    st.m_st = -1.0e30f; st.l_st = 0.f;

    bf16x8 kA[8], kB[8], vv[8];

#define LOADK(dst, itx) do {                                                   \
        const unsigned short* _p = KFh + (size_t)(itx) * 4096 + lane * 8;      \
        dst[0] = *(const bf16x8*)(_p + 0 * 512);                               \
        dst[1] = *(const bf16x8*)(_p + 1 * 512);                               \
        dst[2] = *(const bf16x8*)(_p + 2 * 512);                               \
        dst[3] = *(const bf16x8*)(_p + 3 * 512);                               \
        dst[4] = *(const bf16x8*)(_p + 4 * 512);                               \
        dst[5] = *(const bf16x8*)(_p + 5 * 512);                               \
        dst[6] = *(const bf16x8*)(_p + 6 * 512);                               \
        dst[7] = *(const bf16x8*)(_p + 7 * 512);                               \
    } while (0)

#define LOADV(dst, itx) do {                                                   \
        const unsigned short* _p = VFh + (size_t)(itx) * 4096 + lane * 8;      \
        dst[0] = *(const bf16x8*)(_p + 0 * 512);                               \
        dst[1] = *(const bf16x8*)(_p + 1 * 512);                               \
        dst[2] = *(const bf16x8*)(_p + 2 * 512);                               \
        dst[3] = *(const bf16x8*)(_p + 3 * 512);                               \
        dst[4] = *(const bf16x8*)(_p + 4 * 512);                               \
        dst[5] = *(const bf16x8*)(_p + 5 * 512);                               \
        dst[6] = *(const bf16x8*)(_p + 6 * 512);                               \
        dst[7] = *(const bf16x8*)(_p + 7 * 512);                               \
    } while (0)

    LOADK(kA, 0);
    #pragma unroll 1
    for (int ii = 0; ii < 8; ++ii) {
        const int itE = ii * 2, itO = itE + 1;
        const int mE = mk[itE * 64 + lane];
        LOADV(vv, itE);
        LOADK(kB, itO);
        __builtin_amdgcn_sched_barrier(0);
        attn_step(kA, vv, qf, mE, brow, lane, hi, st);
        const int mO = mk[itO * 64 + lane];
        const int itN = itO + 1 > 15 ? 15 : itO + 1;
        LOADV(vv, itO);
        LOADK(kA, itN);
        __builtin_amdgcn_sched_barrier(0);
        attn_step(kB, vv, qf, mO, brow, lane, hi, st);
    }
#undef LOADK
#undef LOADV

    const float inv = st.l_st > 0.f ? 1.f / st.l_st : 0.f;
    unsigned short* Xp = Xb + (size_t)(b * NS + q) * ND + h * 64 + 4 * hi;
    #pragma unroll
    for (int mm = 0; mm < 4; ++mm) {
        unsigned w0, w1;
        CVTPK(w0, st.acc0[4 * mm] * inv, st.acc0[4 * mm + 1] * inv);
        CVTPK(w1, st.acc0[4 * mm + 2] * inv, st.acc0[4 * mm + 3] * inv);
        uint2 pv; pv.x = w0; pv.y = w1;
        *(uint2*)(Xp + 8 * mm) = pv;
        CVTPK(w0, st.acc1[4 * mm] * inv, st.acc1[4 * mm + 1] * inv);
        CVTPK(w1, st.acc1[4 * mm + 2] * inv, st.acc1[4 * mm + 3] * inv);
        pv.x = w0; pv.y = w1;
        *(uint2*)(Xp + 32 + 8 * mm) = pv;
    }
}

// ---------------------------------------------------------------------------
// Host launcher. Workspace (bf16 elements): wt(4*512*512), QF, KF, VF, Xb.
// ---------------------------------------------------------------------------
extern "C" void kernel_launch(void* const* d_in, const int* in_sizes, int n_in,
                              void* d_out, int out_size, void* d_ws, size_t ws_size,
                              hipStream_t stream) {
    const float* query = (const float*)d_in[0];
    const float* key   = (const float*)d_in[1];
    const float* value = (const float*)d_in[2];
    const int*   mask  = (const int*)d_in[3];
    const float* Wq = (const float*)d_in[4];
    const float* bq = (const float*)d_in[5];
    const float* Wk = (const float*)d_in[6];
    const float* bk = (const float*)d_in[7];
    const float* Wv = (const float*)d_in[8];
    const float* bv = (const float*)d_in[9];
    const float* Wo = (const float*)d_in[10];
    const float* bo = (const float*)d_in[11];

    const size_t HEADSZ = (size_t)NB * NH * NS * NDK;  // 4194304
    unsigned short* wt = (unsigned short*)d_ws;
    unsigned short* QFb = wt + (size_t)4 * ND * ND;
    unsigned short* KFb = QFb + HEADSZ;
    unsigned short* VFb = KFb + HEADSZ;
    unsigned short* Xb  = VFb + HEADSZ;

    // 1. weights -> bf16, transposed
    wt_kernel<<<dim3(8, 8, 4), 256, 0, stream>>>(Wq, Wk, Wv, Wo, wt);

    // 2. QKV projections into fragment-major layouts (z = q/k/v)
    gemm_qkv<<<768, 256, 0, stream>>>(query, key, value, wt, bq, bk, bv, QFb);

    // 3. attention (512 blocks, 4 waves each, no barriers)
    attn_kernel<<<512, 256, 0, stream>>>(QFb, KFb, VFb, mask, Xb);

    // 4. output projection (fp32 out)
    gemm_out<<<512, 256, 0, stream>>>(Xb, wt + (size_t)3 * ND * ND, bo, (float*)d_out);
}

// Round 11
// 80.468 us; speedup vs baseline: 1.0293x; 1.0189x over previous
//
#include <hip/hip_runtime.h>
#include <hip/hip_bf16.h>

// Shapes (fixed by the reference)
#define NB 8
#define NS 1024
#define ND 512
#define NH 8
#define NDK 64

typedef __attribute__((ext_vector_type(8))) short bf16x8;
typedef __attribute__((ext_vector_type(4))) float f32x4;
typedef __attribute__((ext_vector_type(16))) float f32x16;

// scores are computed in exp2 domain: Q is pre-scaled by 0.125 * log2(e)
#define QSCALE 0.18033688011112042f
#define NEGBIG -3.0e38f

#define CVTPK(dst, a, b) \
    asm("v_cvt_pk_bf16_f32 %0, %1, %2" : "=v"(dst) : "v"(a), "v"(b))
#define PLSWAP(a, b) \
    asm("v_permlane32_swap_b32 %0, %1" : "+v"(a), "+v"(b))

__device__ __forceinline__ unsigned short bfround(float f) {
    union { float f; unsigned u; } v; v.f = f;
    unsigned u = v.u;
    u += 0x7fffu + ((u >> 16) & 1u);
    return (unsigned short)(u >> 16);
}

// ---------------------------------------------------------------------------
// Fragment-major global layouts for attention operands (16B chunk = 8 shorts;
// chunk c of head = head_base + c*512 + lane*8; see attn LOADK/LOADV).
//   QF: chunk=(s>>5)*4+(dk>>4),              lane=((dk>>3)&1)*32+(s&31), e=dk&7
//   KF: chunk=(s>>6)*8+((s>>5)&1)*4+(dk>>4), lane=((dk>>3)&1)*32+(s&31), e=dk&7
//   VF: chunk=(s>>6)*8+(dk>>5)*4+((s>>4)&3), lane=((s>>3)&1)*32+(dk&31), e=s&7
// ---------------------------------------------------------------------------

// ---------------------------------------------------------------------------
// Kernel 1: transpose + convert the four 512x512 fp32 weights ([in][out]) into
// bf16 Wt[out][in].
// ---------------------------------------------------------------------------
__global__ __launch_bounds__(256) void wt_kernel(const float* __restrict__ W0,
                                                 const float* __restrict__ W1,
                                                 const float* __restrict__ W2,
                                                 const float* __restrict__ W3,
                                                 unsigned short* __restrict__ wt) {
    __shared__ float sh[64][65];
    const int z = blockIdx.z;
    const float* W = z == 0 ? W0 : z == 1 ? W1 : z == 2 ? W2 : W3;
    unsigned short* out = wt + (size_t)z * ND * ND;
    const int o0 = blockIdx.x * 64, i0 = blockIdx.y * 64;
    const int tx = threadIdx.x & 63;
    const int ty = threadIdx.x >> 6;  // 0..3
    #pragma unroll
    for (int rr = 0; rr < 16; ++rr) {
        const int row = ty * 16 + rr;  // local i
        sh[row][tx] = W[(size_t)(i0 + row) * ND + o0 + tx];
    }
    __syncthreads();
    #pragma unroll
    for (int rr = 0; rr < 16; ++rr) {
        const int row = ty * 16 + rr;  // local o
        out[(size_t)(o0 + row) * ND + i0 + tx] = bfround(sh[tx][row]);
    }
}

// ---------------------------------------------------------------------------
// Kernel 2: QKV projection GEMM. R5-R9 were stuck at ~42-45us with every pipe
// idle: grid 768 = 3 blocks/CU (tile-capped TLP) + a 2B-scalar scatter
// epilogue (32 stores/thread at 16B stride, heavy addr math). Now:
//  - tile 64x128 (A is fp32: small M-tile minimizes staging bytes): grid 1536
//    = 6 blocks/CU, LDS 30.75KB -> 5 resident (launch_bounds(256,5)).
//  - reg-staged all-bf16 pad-40 LDS (R9 structure, verified even bank tiling)
//  - epilogue: acc -> XOR-swizzled LDS bf16 tile (z=2 transposed), then each
//    lane stores one 16B fragment-major chunk slice: 4 dwordx4 stores/thread
//    replacing 32 scalar u16 stores.
// Waves 2x2: wave-tile 32m x 64n, acc[2][4], 8 MFMA/K-step.
// LDS sub-buffers addressed by inline offset (R10's const-pointer arrays of
// LDS addresses fail to compile: addrspacecast static initializer).
//   AL(p) = SM + p*2560        [64][40]
//   BL(p) = SM + 5120 + p*5120 [128][40]
// ---------------------------------------------------------------------------
__global__ __launch_bounds__(256, 5) void gemm_qkv(
    const float* __restrict__ A0, const float* __restrict__ A1, const float* __restrict__ A2,
    const unsigned short* __restrict__ wt,
    const float* __restrict__ b0, const float* __restrict__ b1, const float* __restrict__ b2,
    unsigned short* __restrict__ outb) {
    __shared__ unsigned short SM[15360];  // staging 30720B; epilogue bounce 16KB
    const int t = threadIdx.x;
    const int lane = t & 63, w = t >> 6;
    const int wr = w >> 1, wc = w & 1;
    const int lr = lane & 15, lg = lane >> 4;
    const int bid = blockIdx.x;               // 1536 blocks
    const int u = (bid & 7) * 192 + (bid >> 3);
    const int xt = u & 3, yt = (u >> 2) & 127, z = u >> 9;
    const float* A = z == 0 ? A0 : z == 1 ? A1 : A2;
    const float* bias = z == 0 ? b0 : z == 1 ? b1 : b2;
    const unsigned short* Wt = wt + (size_t)z * ND * ND;
    unsigned short* outp = outb + (size_t)z * NB * NH * NS * NDK;
    const int m0 = yt * 64, n0 = xt * 128;

    // staging geometry
    const int a_row = t >> 3;            // 0..31 (+32 for 2nd chunk)
    const int a_col = (t & 7) * 4;       // fp32 col
    const int b_row = t >> 2;            // 0..63 (+64 for 2nd chunk)
    const int b_col = (t & 3) * 8;

    f32x4 acc[2][4];
    #pragma unroll
    for (int i = 0; i < 2; ++i)
        #pragma unroll
        for (int j = 0; j < 4; ++j) acc[i][j] = (f32x4){0.f, 0.f, 0.f, 0.f};

    f32x4 ra[2];
    bf16x8 rbv[2];

#define QKV_LOAD(kt) do {                                                      \
        const int _k0 = (kt) * 32;                                             \
        ra[0] = *(const f32x4*)(A + (size_t)(m0 + a_row) * ND + _k0 + a_col);  \
        ra[1] = *(const f32x4*)(A + (size_t)(m0 + a_row + 32) * ND + _k0 + a_col); \
        rbv[0] = *(const bf16x8*)(Wt + (size_t)(n0 + b_row) * ND + _k0 + b_col); \
        rbv[1] = *(const bf16x8*)(Wt + (size_t)(n0 + b_row + 64) * ND + _k0 + b_col); \
    } while (0)

#define QKV_WRITE(p) do {                                                      \
        _Pragma("unroll")                                                      \
        for (int j = 0; j < 2; ++j) {                                          \
            unsigned c0, c1;                                                   \
            CVTPK(c0, ra[j][0], ra[j][1]);                                     \
            CVTPK(c1, ra[j][2], ra[j][3]);                                     \
            uint2 pv; pv.x = c0; pv.y = c1;                                    \
            *(uint2*)(&SM[(p) * 2560 + (a_row + j * 32) * 40 + a_col]) = pv;   \
        }                                                                      \
        _Pragma("unroll")                                                      \
        for (int j = 0; j < 2; ++j)                                            \
            *(bf16x8*)(&SM[5120 + (p) * 5120 + (b_row + j * 64) * 40 + b_col]) = rbv[j]; \
    } while (0)

#define QKV_COMPUTE(p) do {                                                    \
        bf16x8 af[2], bfr[4];                                                  \
        _Pragma("unroll")                                                      \
        for (int mi = 0; mi < 2; ++mi)                                         \
            af[mi] = *(const bf16x8*)(&SM[(p) * 2560 + (wr * 32 + mi * 16 + lr) * 40 + lg * 8]); \
        _Pragma("unroll")                                                      \
        for (int nj = 0; nj < 4; ++nj)                                         \
            bfr[nj] = *(const bf16x8*)(&SM[5120 + (p) * 5120 + (wc * 64 + nj * 16 + lr) * 40 + lg * 8]); \
        __builtin_amdgcn_s_setprio(1);                                         \
        _Pragma("unroll")                                                      \
        for (int mi = 0; mi < 2; ++mi)                                         \
            _Pragma("unroll")                                                  \
            for (int nj = 0; nj < 4; ++nj)                                     \
                acc[mi][nj] = __builtin_amdgcn_mfma_f32_16x16x32_bf16(         \
                    af[mi], bfr[nj], acc[mi][nj], 0, 0, 0);                    \
        __builtin_amdgcn_s_setprio(0);                                         \
    } while (0)

    QKV_LOAD(0);
    QKV_WRITE(0);
    QKV_LOAD(1);
    __syncthreads();
    #pragma unroll 1
    for (int kt = 0; kt < 15; ++kt) {
        QKV_COMPUTE(kt & 1);
        QKV_WRITE((kt + 1) & 1);
        if (kt < 14) QKV_LOAD(kt + 2);
        __syncthreads();
    }
    QKV_COMPUTE(1);
#undef QKV_LOAD
#undef QKV_WRITE
#undef QKV_COMPUTE

    // ---- epilogue: LDS bounce -> coalesced fragment-major chunk stores ----
    __syncthreads();   // staging reads done; SM reused as bounce tile
    const float osc = z == 0 ? QSCALE : 1.0f;
    const int bb = m0 >> 10;
    char* const C = (char*)SM;
    if (z <= 1) {
        // bounce [s 64][dk 128] bf16, XOR-swizzled (byte ^= (row&7)<<4)
        #pragma unroll
        for (int mi = 0; mi < 2; ++mi)
            #pragma unroll
            for (int nj = 0; nj < 4; ++nj) {
                const int coln = wc * 64 + nj * 16 + lr;
                const float bv = bias[n0 + coln];
                #pragma unroll
                for (int r = 0; r < 4; ++r) {
                    const int row = wr * 32 + mi * 16 + lg * 4 + r;
                    unsigned off = (unsigned)(row * 256 + coln * 2);
                    off ^= (row & 7) << 4;
                    *(unsigned short*)(C + off) = bfround((acc[mi][nj][r] + bv) * osc);
                }
            }
        __syncthreads();
        // QF and KF chunk bases coincide because m0 % 64 == 0
        const unsigned cb = ((unsigned)(m0 & 1023) >> 5) * 4;
        #pragma unroll
        for (int cc = 0; cc < 4; ++cc) {
            const int c = w * 4 + cc;                 // 0..15
            const int sub = c >> 3, hhl = (c >> 2) & 1, kk = c & 3;
            const int row = sub * 32 + (lane & 31);
            unsigned off = (unsigned)(row * 256 + (hhl * 64 + kk * 16 + (lane >> 5) * 8) * 2);
            off ^= (row & 7) << 4;
            const bf16x8 v8 = *(const bf16x8*)(C + off);
            const int hh = xt * 2 + hhl;
            *(bf16x8*)(outp + (((size_t)(bb * NH + hh)) << 16) +
                       (size_t)(cb + sub * 4 + kk) * 512 + lane * 8) = v8;
        }
    } else {
        // bounce TRANSPOSED [dk 128][s 64] bf16, XOR-swizzled
        #pragma unroll
        for (int mi = 0; mi < 2; ++mi)
            #pragma unroll
            for (int nj = 0; nj < 4; ++nj) {
                const int dkl = wc * 64 + nj * 16 + lr;
                const float bv = bias[n0 + dkl];
                #pragma unroll
                for (int r = 0; r < 4; ++r) {
                    const int sl = wr * 32 + mi * 16 + lg * 4 + r;
                    unsigned off = (unsigned)(dkl * 128 + sl * 2);
                    off ^= (dkl & 7) << 4;
                    *(unsigned short*)(C + off) = bfround(acc[mi][nj][r] + bv);
                }
            }
        __syncthreads();
        const unsigned it8 = ((unsigned)(m0 & 1023) >> 6) * 8;
        #pragma unroll
        for (int cc = 0; cc < 4; ++cc) {
            const int c = w * 4 + cc;                 // 0..15
            const int hhl = c >> 3, od = (c >> 2) & 1, s4 = c & 3;
            const int row = hhl * 64 + od * 32 + (lane & 31);
            unsigned off = (unsigned)(row * 128 + (s4 * 16 + (lane >> 5) * 8) * 2);
            off ^= (row & 7) << 4;
            const bf16x8 v8 = *(const bf16x8*)(C + off);
            const int hh = xt * 2 + hhl;
            *(bf16x8*)(outp + (((size_t)(bb * NH + hh)) << 16) +
                       (size_t)(it8 + od * 4 + s4) * 512 + lane * 8) = v8;
        }
    }
}

// ---------------------------------------------------------------------------
// Kernel 4: output projection GEMM, 64x64 tiles (1024 blocks = 4/CU),
// reg-staged pad-40, waves 2x2 (wave-tile 32x32, acc[2][2]). fp32 coalesced
// epilogue. LDS sub-buffers by inline offset:
//   Ao(p) = SM2 + p*2560; Bo(p) = SM2 + 5120 + p*2560.
// ---------------------------------------------------------------------------
__global__ __launch_bounds__(256) void gemm_out(
    const unsigned short* __restrict__ Xb, const unsigned short* __restrict__ Wt,
    const float* __restrict__ bo, float* __restrict__ outp) {
    __shared__ unsigned short SM2[10240];
    const int t = threadIdx.x;
    const int lane = t & 63, w = t >> 6;
    const int wr = w >> 1, wc = w & 1;
    const int lr = lane & 15, lg = lane >> 4;
    const int bid = blockIdx.x;               // 1024 blocks
    const int u = (bid & 7) * 128 + (bid >> 3);
    const int xt = u & 7, yt = u >> 3;
    const int m0 = yt * 64, n0 = xt * 64;

    const int s_row = t >> 2;          // 0..63
    const int s_col = (t & 3) * 8;

    f32x4 acc[2][2];
    #pragma unroll
    for (int i = 0; i < 2; ++i)
        #pragma unroll
        for (int j = 0; j < 2; ++j) acc[i][j] = (f32x4){0.f, 0.f, 0.f, 0.f};

    bf16x8 raa, rbb;

#define OUT_LOAD(kt) do {                                                      \
        const int _k0 = (kt) * 32;                                             \
        raa = *(const bf16x8*)(Xb + (size_t)(m0 + s_row) * ND + _k0 + s_col);  \
        rbb = *(const bf16x8*)(Wt + (size_t)(n0 + s_row) * ND + _k0 + s_col);  \
    } while (0)

#define OUT_WRITE(p) do {                                                      \
        *(bf16x8*)(&SM2[(p) * 2560 + s_row * 40 + s_col]) = raa;               \
        *(bf16x8*)(&SM2[5120 + (p) * 2560 + s_row * 40 + s_col]) = rbb;        \
    } while (0)

#define OUT_COMPUTE(p) do {                                                    \
        bf16x8 af[2], bfr[2];                                                  \
        _Pragma("unroll")                                                      \
        for (int mi = 0; mi < 2; ++mi)                                         \
            af[mi] = *(const bf16x8*)(&SM2[(p) * 2560 + (wr * 32 + mi * 16 + lr) * 40 + lg * 8]); \
        _Pragma("unroll")                                                      \
        for (int nj = 0; nj < 2; ++nj)                                         \
            bfr[nj] = *(const bf16x8*)(&SM2[5120 + (p) * 2560 + (wc * 32 + nj * 16 + lr) * 40 + lg * 8]); \
        __builtin_amdgcn_s_setprio(1);                                         \
        _Pragma("unroll")                                                      \
        for (int mi = 0; mi < 2; ++mi)                                         \
            _Pragma("unroll")                                                  \
            for (int nj = 0; nj < 2; ++nj)                                     \
                acc[mi][nj] = __builtin_amdgcn_mfma_f32_16x16x32_bf16(         \
                    af[mi], bfr[nj], acc[mi][nj], 0, 0, 0);                    \
        __builtin_amdgcn_s_setprio(0);                                         \
    } while (0)

    OUT_LOAD(0);
    OUT_WRITE(0);
    OUT_LOAD(1);
    __syncthreads();
    #pragma unroll 1
    for (int kt = 0; kt < 15; ++kt) {
        OUT_COMPUTE(kt & 1);
        OUT_WRITE((kt + 1) & 1);
        if (kt < 14) OUT_LOAD(kt + 2);
        __syncthreads();
    }
    OUT_COMPUTE(1);
#undef OUT_LOAD
#undef OUT_WRITE
#undef OUT_COMPUTE

    #pragma unroll
    for (int mi = 0; mi < 2; ++mi) {
        #pragma unroll
        for (int nj = 0; nj < 2; ++nj) {
            const int n = n0 + wc * 32 + nj * 16 + lr;
            const float bv = bo[n];
            #pragma unroll
            for (int r = 0; r < 4; ++r) {
                const int m = m0 + wr * 32 + mi * 16 + lg * 4 + r;
                outp[(size_t)m * ND + n] = acc[mi][nj][r] + bv;
            }
        }
    }
}

// ---------------------------------------------------------------------------
// Kernel 3: flash attention (unchanged from R5-R9 — fragment-major coalesced
// loads, swapped-operand 32x32 MFMA, in-register softmax, K double-buffer).
// ---------------------------------------------------------------------------
struct AttnState {
    f32x16 acc0, acc1;
    float m_st, l_st;
};

__device__ __forceinline__ void attn_step(const bf16x8 (&kf)[8], const bf16x8 (&vv)[8],
                                          const bf16x8 (&qf)[4], int mval,
                                          float* __restrict__ brow, int lane, int hi,
                                          AttnState& st) {
    brow[lane] = mval ? 0.f : NEGBIG;

    f32x16 sc0 = {}, sc1 = {};
    __builtin_amdgcn_s_setprio(1);
    sc0 = __builtin_amdgcn_mfma_f32_32x32x16_bf16(kf[0], qf[0], sc0, 0, 0, 0);
    sc1 = __builtin_amdgcn_mfma_f32_32x32x16_bf16(kf[4], qf[0], sc1, 0, 0, 0);
    sc0 = __builtin_amdgcn_mfma_f32_32x32x16_bf16(kf[1], qf[1], sc0, 0, 0, 0);
    sc1 = __builtin_amdgcn_mfma_f32_32x32x16_bf16(kf[5], qf[1], sc1, 0, 0, 0);
    sc0 = __builtin_amdgcn_mfma_f32_32x32x16_bf16(kf[2], qf[2], sc0, 0, 0, 0);
    sc1 = __builtin_amdgcn_mfma_f32_32x32x16_bf16(kf[6], qf[2], sc1, 0, 0, 0);
    sc0 = __builtin_amdgcn_mfma_f32_32x32x16_bf16(kf[3], qf[3], sc0, 0, 0, 0);
    sc1 = __builtin_amdgcn_mfma_f32_32x32x16_bf16(kf[7], qf[3], sc1, 0, 0, 0);
    __builtin_amdgcn_s_setprio(0);

    {
        const float* bl = brow + 4 * hi;
        #pragma unroll
        for (int mm = 0; mm < 4; ++mm) {
            const f32x4 bv0 = *(const f32x4*)(bl + 8 * mm);
            const f32x4 bv1 = *(const f32x4*)(bl + 32 + 8 * mm);
            #pragma unroll
            for (int c = 0; c < 4; ++c) {
                sc0[4 * mm + c] += bv0[c];
                sc1[4 * mm + c] += bv1[c];
            }
        }
    }

    float tv[16];
    #pragma unroll
    for (int r = 0; r < 16; ++r) tv[r] = fmaxf(sc0[r], sc1[r]);
    #pragma unroll
    for (int s = 8; s > 0; s >>= 1)
        #pragma unroll
        for (int r = 0; r < 16; ++r)
            if (r < s) tv[r] = fmaxf(tv[r], tv[r + s]);
    const float mx = fmaxf(tv[0], __shfl_xor(tv[0], 32));
    const float mn = fmaxf(st.m_st, mx);

    #pragma unroll
    for (int r = 0; r < 16; ++r) {
        sc0[r] = __builtin_amdgcn_exp2f(sc0[r] - mn);
        sc1[r] = __builtin_amdgcn_exp2f(sc1[r] - mn);
    }
    #pragma unroll
    for (int r = 0; r < 16; ++r) tv[r] = sc0[r] + sc1[r];
    #pragma unroll
    for (int s = 8; s > 0; s >>= 1)
        #pragma unroll
        for (int r = 0; r < 16; ++r)
            if (r < s) tv[r] += tv[r + s];
    const float rs = tv[0] + __shfl_xor(tv[0], 32);

    const bool ch = mn > st.m_st;
    if (__any(ch)) {
        const float f = __builtin_amdgcn_exp2f(st.m_st - mn);
        st.l_st = st.l_st * f + rs;
        st.m_st = mn;
        #pragma unroll
        for (int r = 0; r < 16; ++r) { st.acc0[r] *= f; st.acc1[r] *= f; }
    } else {
        st.l_st += rs;
    }

    union U8 { unsigned u[4]; bf16x8 v; };
    bf16x8 pA0, pA1, pB0, pB1;
    {
        unsigned w00, w01, w10, w11, w20, w21, w30, w31;
        CVTPK(w00, sc0[0], sc0[1]);  CVTPK(w01, sc0[2], sc0[3]);
        CVTPK(w10, sc0[4], sc0[5]);  CVTPK(w11, sc0[6], sc0[7]);
        CVTPK(w20, sc0[8], sc0[9]);  CVTPK(w21, sc0[10], sc0[11]);
        CVTPK(w30, sc0[12], sc0[13]); CVTPK(w31, sc0[14], sc0[15]);
        PLSWAP(w00, w10); PLSWAP(w01, w11);
        PLSWAP(w20, w30); PLSWAP(w21, w31);
        U8 f0; f0.u[0] = w00; f0.u[1] = w01; f0.u[2] = w10; f0.u[3] = w11;
        U8 f1; f1.u[0] = w20; f1.u[1] = w21; f1.u[2] = w30; f1.u[3] = w31;
        pA0 = f0.v; pA1 = f1.v;
    }
    {
        unsigned w00, w01, w10, w11, w20, w21, w30, w31;
        CVTPK(w00, sc1[0], sc1[1]);  CVTPK(w01, sc1[2], sc1[3]);
        CVTPK(w10, sc1[4], sc1[5]);  CVTPK(w11, sc1[6], sc1[7]);
        CVTPK(w20, sc1[8], sc1[9]);  CVTPK(w21, sc1[10], sc1[11]);
        CVTPK(w30, sc1[12], sc1[13]); CVTPK(w31, sc1[14], sc1[15]);
        PLSWAP(w00, w10); PLSWAP(w01, w11);
        PLSWAP(w20, w30); PLSWAP(w21, w31);
        U8 f0; f0.u[0] = w00; f0.u[1] = w01; f0.u[2] = w10; f0.u[3] = w11;
        U8 f1; f1.u[0] = w20; f1.u[1] = w21; f1.u[2] = w30; f1.u[3] = w31;
        pB0 = f0.v; pB1 = f1.v;
    }

    __builtin_amdgcn_s_setprio(1);
    st.acc0 = __builtin_amdgcn_mfma_f32_32x32x16_bf16(vv[0], pA0, st.acc0, 0, 0, 0);
    st.acc1 = __builtin_amdgcn_mfma_f32_32x32x16_bf16(vv[4], pA0, st.acc1, 0, 0, 0);
    st.acc0 = __builtin_amdgcn_mfma_f32_32x32x16_bf16(vv[1], pA1, st.acc0, 0, 0, 0);
    st.acc1 = __builtin_amdgcn_mfma_f32_32x32x16_bf16(vv[5], pA1, st.acc1, 0, 0, 0);
    st.acc0 = __builtin_amdgcn_mfma_f32_32x32x16_bf16(vv[2], pB0, st.acc0, 0, 0, 0);
    st.acc1 = __builtin_amdgcn_mfma_f32_32x32x16_bf16(vv[6], pB0, st.acc1, 0, 0, 0);
    st.acc0 = __builtin_amdgcn_mfma_f32_32x32x16_bf16(vv[3], pB1, st.acc0, 0, 0, 0);
    st.acc1 = __builtin_amdgcn_mfma_f32_32x32x16_bf16(vv[7], pB1, st.acc1, 0, 0, 0);
    __builtin_amdgcn_s_setprio(0);
}

__global__ __launch_bounds__(256, 2) void attn_kernel(const unsigned short* __restrict__ QF,
                                                      const unsigned short* __restrict__ KF,
                                                      const unsigned short* __restrict__ VF,
                                                      const int* __restrict__ mask,
                                                      unsigned short* __restrict__ Xb) {
    __shared__ float bias_lds[4][64];
    const int t = threadIdx.x;
    const int lane = t & 63, w = t >> 6;
    const int q32 = lane & 31, hi = lane >> 5;
    const int bid = blockIdx.x;                  // 512 blocks
    const int u = (bid & 7) * 64 + (bid >> 3);
    const int bh = u >> 3, xq = u & 7;
    const int b = bh >> 3, h = bh & 7;
    const int q = xq * 128 + w * 32 + q32;
    const unsigned short* QFh = QF + ((size_t)bh << 16);
    const unsigned short* KFh = KF + ((size_t)bh << 16);
    const unsigned short* VFh = VF + ((size_t)bh << 16);
    const int* mk = mask + b * NS;
    float* brow = &bias_lds[w][0];

    bf16x8 qf[4];
    {
        const unsigned short* Qp = QFh + (size_t)(xq * 16 + w * 4) * 512 + lane * 8;
        qf[0] = *(const bf16x8*)(Qp + 0 * 512);
        qf[1] = *(const bf16x8*)(Qp + 1 * 512);
        qf[2] = *(const bf16x8*)(Qp + 2 * 512);
        qf[3] = *(const bf16x8*)(Qp + 3 * 512);
    }

    AttnState st;
    st.acc0 = (f32x16){}; st.acc1 = (f32x16){};
    st.m_st = -1.0e30f; st.l_st = 0.f;

    bf16x8 kA[8], kB[8], vv[8];

#define LOADK(dst, itx) do {                                                   \
        const unsigned short* _p = KFh + (size_t)(itx) * 4096 + lane * 8;      \
        dst[0] = *(const bf16x8*)(_p + 0 * 512);                               \
        dst[1] = *(const bf16x8*)(_p + 1 * 512);                               \
        dst[2] = *(const bf16x8*)(_p + 2 * 512);                               \
        dst[3] = *(const bf16x8*)(_p + 3 * 512);                               \
        dst[4] = *(const bf16x8*)(_p + 4 * 512);                               \
        dst[5] = *(const bf16x8*)(_p + 5 * 512);                               \
        dst[6] = *(const bf16x8*)(_p + 6 * 512);                               \
        dst[7] = *(const bf16x8*)(_p + 7 * 512);                               \
    } while (0)

#define LOADV(dst, itx) do {                                                   \
        const unsigned short* _p = VFh + (size_t)(itx) * 4096 + lane * 8;      \
        dst[0] = *(const bf16x8*)(_p + 0 * 512);                               \
        dst[1] = *(const bf16x8*)(_p + 1 * 512);                               \
        dst[2] = *(const bf16x8*)(_p + 2 * 512);                               \
        dst[3] = *(const bf16x8*)(_p + 3 * 512);                               \
        dst[4] = *(const bf16x8*)(_p + 4 * 512);                               \
        dst[5] = *(const bf16x8*)(_p + 5 * 512);                               \
        dst[6] = *(const bf16x8*)(_p + 6 * 512);                               \
        dst[7] = *(const bf16x8*)(_p + 7 * 512);                               \
    } while (0)

    LOADK(kA, 0);
    #pragma unroll 1
    for (int ii = 0; ii < 8; ++ii) {
        const int itE = ii * 2, itO = itE + 1;
        const int mE = mk[itE * 64 + lane];
        LOADV(vv, itE);
        LOADK(kB, itO);
        __builtin_amdgcn_sched_barrier(0);
        attn_step(kA, vv, qf, mE, brow, lane, hi, st);
        const int mO = mk[itO * 64 + lane];
        const int itN = itO + 1 > 15 ? 15 : itO + 1;
        LOADV(vv, itO);
        LOADK(kA, itN);
        __builtin_amdgcn_sched_barrier(0);
        attn_step(kB, vv, qf, mO, brow, lane, hi, st);
    }
#undef LOADK
#undef LOADV

    const float inv = st.l_st > 0.f ? 1.f / st.l_st : 0.f;
    unsigned short* Xp = Xb + (size_t)(b * NS + q) * ND + h * 64 + 4 * hi;
    #pragma unroll
    for (int mm = 0; mm < 4; ++mm) {
        unsigned w0, w1;
        CVTPK(w0, st.acc0[4 * mm] * inv, st.acc0[4 * mm + 1] * inv);
        CVTPK(w1, st.acc0[4 * mm + 2] * inv, st.acc0[4 * mm + 3] * inv);
        uint2 pv; pv.x = w0; pv.y = w1;
        *(uint2*)(Xp + 8 * mm) = pv;
        CVTPK(w0, st.acc1[4 * mm] * inv, st.acc1[4 * mm + 1] * inv);
        CVTPK(w1, st.acc1[4 * mm + 2] * inv, st.acc1[4 * mm + 3] * inv);
        pv.x = w0; pv.y = w1;
        *(uint2*)(Xp + 32 + 8 * mm) = pv;
    }
}

// ---------------------------------------------------------------------------
// Host launcher. Workspace (bf16 elements): wt(4*512*512), QF, KF, VF, Xb.
// ---------------------------------------------------------------------------
extern "C" void kernel_launch(void* const* d_in, const int* in_sizes, int n_in,
                              void* d_out, int out_size, void* d_ws, size_t ws_size,
                              hipStream_t stream) {
    const float* query = (const float*)d_in[0];
    const float* key   = (const float*)d_in[1];
    const float* value = (const float*)d_in[2];
    const int*   mask  = (const int*)d_in[3];
    const float* Wq = (const float*)d_in[4];
    const float* bq = (const float*)d_in[5];
    const float* Wk = (const float*)d_in[6];
    const float* bk = (const float*)d_in[7];
    const float* Wv = (const float*)d_in[8];
    const float* bv = (const float*)d_in[9];
    const float* Wo = (const float*)d_in[10];
    const float* bo = (const float*)d_in[11];

    const size_t HEADSZ = (size_t)NB * NH * NS * NDK;  // 4194304
    unsigned short* wt = (unsigned short*)d_ws;
    unsigned short* QFb = wt + (size_t)4 * ND * ND;
    unsigned short* KFb = QFb + HEADSZ;
    unsigned short* VFb = KFb + HEADSZ;
    unsigned short* Xb  = VFb + HEADSZ;

    // 1. weights -> bf16, transposed
    wt_kernel<<<dim3(8, 8, 4), 256, 0, stream>>>(Wq, Wk, Wv, Wo, wt);

    // 2. QKV projections into fragment-major layouts (z = q/k/v)
    gemm_qkv<<<1536, 256, 0, stream>>>(query, key, value, wt, bq, bk, bv, QFb);

    // 3. attention (512 blocks, 4 waves each, no barriers)
    attn_kernel<<<512, 256, 0, stream>>>(QFb, KFb, VFb, mask, Xb);

    // 4. output projection (fp32 out)
    gemm_out<<<1024, 256, 0, stream>>>(Xb, wt + (size_t)3 * ND * ND, bo, (float*)d_out);
}

// Round 13
// 77.665 us; speedup vs baseline: 1.0665x; 1.0361x over previous
//
#include <hip/hip_runtime.h>
#include <hip/hip_bf16.h>

// Shapes (fixed by the reference)
#define NB 8
#define NS 1024
#define ND 512
#define NH 8
#define NDK 64

typedef __attribute__((ext_vector_type(8))) short bf16x8;
typedef __attribute__((ext_vector_type(4))) float f32x4;
typedef __attribute__((ext_vector_type(16))) float f32x16;

// scores are computed in exp2 domain: Q is pre-scaled by 0.125 * log2(e)
#define QSCALE 0.18033688011112042f
#define NEGBIG -3.0e38f

#define CVTPK(dst, a, b) \
    asm("v_cvt_pk_bf16_f32 %0, %1, %2" : "=v"(dst) : "v"(a), "v"(b))
#define PLSWAP(a, b) \
    asm("v_permlane32_swap_b32 %0, %1" : "+v"(a), "+v"(b))

__device__ __forceinline__ unsigned short bfround(float f) {
    union { float f; unsigned u; } v; v.f = f;
    unsigned u = v.u;
    u += 0x7fffu + ((u >> 16) & 1u);
    return (unsigned short)(u >> 16);
}

// ---------------------------------------------------------------------------
// Fragment-major global layouts for attention operands (16B chunk = 8 shorts;
// chunk c of head = head_base + c*512 + lane*8; see attn LOADK/LOADV).
//   QF: chunk=(s>>5)*4+(dk>>4),              lane=((dk>>3)&1)*32+(s&31), e=dk&7
//   KF: chunk=(s>>6)*8+((s>>5)&1)*4+(dk>>4), lane=((dk>>3)&1)*32+(s&31), e=dk&7
//   VF: chunk=(s>>6)*8+(dk>>5)*4+((s>>4)&3), lane=((s>>3)&1)*32+(dk&31), e=s&7
// ---------------------------------------------------------------------------

// ---------------------------------------------------------------------------
// Kernel 1: transpose + convert the four 512x512 fp32 weights ([in][out]) into
// bf16 Wt[out][in].
// ---------------------------------------------------------------------------
__global__ __launch_bounds__(256) void wt_kernel(const float* __restrict__ W0,
                                                 const float* __restrict__ W1,
                                                 const float* __restrict__ W2,
                                                 const float* __restrict__ W3,
                                                 unsigned short* __restrict__ wt) {
    __shared__ float sh[64][65];
    const int z = blockIdx.z;
    const float* W = z == 0 ? W0 : z == 1 ? W1 : z == 2 ? W2 : W3;
    unsigned short* out = wt + (size_t)z * ND * ND;
    const int o0 = blockIdx.x * 64, i0 = blockIdx.y * 64;
    const int tx = threadIdx.x & 63;
    const int ty = threadIdx.x >> 6;  // 0..3
    #pragma unroll
    for (int rr = 0; rr < 16; ++rr) {
        const int row = ty * 16 + rr;  // local i
        sh[row][tx] = W[(size_t)(i0 + row) * ND + o0 + tx];
    }
    __syncthreads();
    #pragma unroll
    for (int rr = 0; rr < 16; ++rr) {
        const int row = ty * 16 + rr;  // local o
        out[(size_t)(o0 + row) * ND + i0 + tx] = bfround(sh[tx][row]);
    }
}

// ---------------------------------------------------------------------------
// Kernel 2: QKV projection GEMM (R12 design, bugs fixed).
// Tile 128m x 128n, BK=64 -> 8 K-steps of 32 MFMA/wave (2x the R9 per-phase
// compute); z = blockIdx.y; 256 blocks/z, bijective XCD swizzle
// u=(bid&7)*32+(bid>>3) (R12 used the 512-block formula -> OOB crash).
// LDS 27648 shorts = 55.3KB (R12 under-declared 25600): A dbuf 2x[128][72]
// bf16 + B single [128][72] (pad-72: 144B row stride = +4 banks/row, 2-way
// reads free; B single-buffered, consumed then rewritten after sync).
// Reg-staged: fp32 A cvt'd at write; loads for tile kt+2 issued during
// phase kt (coverage ~1 phase of compute).
// Epilogue: XOR-swizzled LDS bounce -> coalesced b128 fragment-major stores
// (chunk maps verified against QF/KF/VF formulas symbolically).
// ---------------------------------------------------------------------------
__global__ __launch_bounds__(256) void gemm_qkv(
    const float* __restrict__ A0, const float* __restrict__ A1, const float* __restrict__ A2,
    const unsigned short* __restrict__ wt,
    const float* __restrict__ b0, const float* __restrict__ b1, const float* __restrict__ b2,
    unsigned short* __restrict__ outb) {
    __shared__ unsigned short SM[27648];  // 55.3KB staging; epilogue bounce 32KB
    const int t = threadIdx.x;
    const int lane = t & 63, w = t >> 6;
    const int wr = w >> 1, wc = w & 1;
    const int lr = lane & 15, lg = lane >> 4;
    const int bid = blockIdx.x;               // 256 blocks per z
    const int u = (bid & 7) * 32 + (bid >> 3);   // bijective XCD swizzle
    const int xt = u & 3, yt = u >> 2;           // xt 0..3, yt 0..63
    const int z = blockIdx.y;
    const float* A = z == 0 ? A0 : z == 1 ? A1 : A2;
    const float* bias = z == 0 ? b0 : z == 1 ? b1 : b2;
    const unsigned short* Wt = wt + (size_t)z * ND * ND;
    unsigned short* outp = outb + (size_t)z * NB * NH * NS * NDK;
    const int m0 = yt * 128, n0 = xt * 128;

    // staging geometry (BK=64):
    // A: per thread 8 f32x4: rows a_row+16j (j=0..7), fp32 cols a_col..a_col+3
    // B: per thread 4 bf16x8: rows b_row+32j (j=0..3), cols b_col..b_col+7
    const int a_row = t >> 4;            // 0..15
    const int a_col = (t & 15) * 4;
    const int b_row = t >> 3;            // 0..31
    const int b_col = (t & 7) * 8;

    f32x4 acc[4][4];
    #pragma unroll
    for (int i = 0; i < 4; ++i)
        #pragma unroll
        for (int j = 0; j < 4; ++j) acc[i][j] = (f32x4){0.f, 0.f, 0.f, 0.f};

    f32x4 ra[8];
    bf16x8 rbv[4];

#define AL(p) (SM + (p) * 9216)
#define BLS (SM + 18432)

#define QKV_LOAD(kt) do {                                                      \
        const int _k0 = (kt) * 64;                                             \
        _Pragma("unroll")                                                      \
        for (int j = 0; j < 8; ++j)                                            \
            ra[j] = *(const f32x4*)(A + (size_t)(m0 + a_row + j * 16) * ND + _k0 + a_col); \
        _Pragma("unroll")                                                      \
        for (int j = 0; j < 4; ++j)                                            \
            rbv[j] = *(const bf16x8*)(Wt + (size_t)(n0 + b_row + j * 32) * ND + _k0 + b_col); \
    } while (0)

#define QKV_WRITEA(p) do {                                                     \
        _Pragma("unroll")                                                      \
        for (int j = 0; j < 8; ++j) {                                          \
            unsigned c0, c1;                                                   \
            CVTPK(c0, ra[j][0], ra[j][1]);                                     \
            CVTPK(c1, ra[j][2], ra[j][3]);                                     \
            uint2 pv; pv.x = c0; pv.y = c1;                                    \
            *(uint2*)(&AL(p)[(a_row + j * 16) * 72 + a_col]) = pv;             \
        }                                                                      \
    } while (0)

#define QKV_WRITEB() do {                                                      \
        _Pragma("unroll")                                                      \
        for (int j = 0; j < 4; ++j)                                            \
            *(bf16x8*)(&BLS[(b_row + j * 32) * 72 + b_col]) = rbv[j];          \
    } while (0)

#define QKV_COMPUTE(p) do {                                                    \
        _Pragma("unroll")                                                      \
        for (int kk = 0; kk < 2; ++kk) {                                       \
            bf16x8 af[4], bfr[4];                                              \
            _Pragma("unroll")                                                  \
            for (int mi = 0; mi < 4; ++mi)                                     \
                af[mi] = *(const bf16x8*)(&AL(p)[(wr * 64 + mi * 16 + lr) * 72 + kk * 32 + lg * 8]); \
            _Pragma("unroll")                                                  \
            for (int nj = 0; nj < 4; ++nj)                                     \
                bfr[nj] = *(const bf16x8*)(&BLS[(wc * 64 + nj * 16 + lr) * 72 + kk * 32 + lg * 8]); \
            __builtin_amdgcn_s_setprio(1);                                     \
            _Pragma("unroll")                                                  \
            for (int mi = 0; mi < 4; ++mi)                                     \
                _Pragma("unroll")                                              \
                for (int nj = 0; nj < 4; ++nj)                                 \
                    acc[mi][nj] = __builtin_amdgcn_mfma_f32_16x16x32_bf16(     \
                        af[mi], bfr[nj], acc[mi][nj], 0, 0, 0);                \
            __builtin_amdgcn_s_setprio(0);                                     \
        }                                                                      \
    } while (0)

    QKV_LOAD(0);
    QKV_WRITEA(0);
    QKV_WRITEB();
    QKV_LOAD(1);
    __builtin_amdgcn_sched_barrier(0);
    __syncthreads();
    #pragma unroll 1
    for (int kt = 0; kt < 7; ++kt) {
        QKV_COMPUTE(kt & 1);
        __syncthreads();              // all waves done reading B before rewrite
        QKV_WRITEA((kt + 1) & 1);
        QKV_WRITEB();
        QKV_LOAD(kt + 2 > 7 ? 7 : kt + 2);
        __builtin_amdgcn_sched_barrier(0);
        __syncthreads();
    }
    QKV_COMPUTE(1);
#undef QKV_LOAD
#undef QKV_WRITEA
#undef QKV_WRITEB
#undef QKV_COMPUTE
#undef AL
#undef BLS

    // ---- epilogue: LDS bounce -> coalesced fragment-major chunk stores ----
    __syncthreads();
    const float osc = z == 0 ? QSCALE : 1.0f;
    const int bb = m0 >> 10;
    const unsigned msb = (unsigned)(m0 & 1023);
    char* const C = (char*)SM;
    if (z <= 1) {
        // bounce [s 128][dk 128] bf16 = 32KB, XOR byte ^= (row&7)<<4
        #pragma unroll
        for (int mi = 0; mi < 4; ++mi)
            #pragma unroll
            for (int nj = 0; nj < 4; ++nj) {
                const int coln = wc * 64 + nj * 16 + lr;
                const float bv = bias[n0 + coln];
                #pragma unroll
                for (int r = 0; r < 4; ++r) {
                    const int row = wr * 64 + mi * 16 + lg * 4 + r;
                    unsigned off = (unsigned)(row * 256 + coln * 2);
                    off ^= (row & 7) << 4;
                    *(unsigned short*)(C + off) = bfround((acc[mi][nj][r] + bv) * osc);
                }
            }
        __syncthreads();
        // 32 chunks: sg(4) x hhl(2) x kk(4) -> 8 per wave; each store = 1KB/wave
        #pragma unroll
        for (int cc = 0; cc < 8; ++cc) {
            const int c = w * 8 + cc;                 // 0..31
            const int sg = c >> 3, hhl = (c >> 2) & 1, kk = c & 3;
            const int row = sg * 32 + (lane & 31);
            unsigned off = (unsigned)(row * 256 + (hhl * 64 + kk * 16 + (lane >> 5) * 8) * 2);
            off ^= (row & 7) << 4;
            const bf16x8 v8 = *(const bf16x8*)(C + off);
            const int hh = xt * 2 + hhl;
            const unsigned chunk = z == 0 ? ((msb >> 5) + sg) * 4 + kk
                                          : ((msb >> 6) + (sg >> 1)) * 8 + (sg & 1) * 4 + kk;
            *(bf16x8*)(outp + (((size_t)(bb * NH + hh)) << 16) +
                       (size_t)chunk * 512 + lane * 8) = v8;
        }
    } else {
        // bounce TRANSPOSED [dk 128][s 128] bf16 = 32KB
        #pragma unroll
        for (int mi = 0; mi < 4; ++mi)
            #pragma unroll
            for (int nj = 0; nj < 4; ++nj) {
                const int dkl = wc * 64 + nj * 16 + lr;
                const float bv = bias[n0 + dkl];
                #pragma unroll
                for (int r = 0; r < 4; ++r) {
                    const int sl = wr * 64 + mi * 16 + lg * 4 + r;
                    unsigned off = (unsigned)(dkl * 256 + sl * 2);
                    off ^= (dkl & 7) << 4;
                    *(unsigned short*)(C + off) = bfround(acc[mi][nj][r] + bv);
                }
            }
        __syncthreads();
        // 32 chunks: hhl(2) x s6(2) x od(2) x s4(4) -> 8 per wave
        #pragma unroll
        for (int cc = 0; cc < 8; ++cc) {
            const int c = w * 8 + cc;                 // 0..31
            const int hhl = c >> 4, s6 = (c >> 3) & 1, od = (c >> 2) & 1, s4 = c & 3;
            const int row = hhl * 64 + od * 32 + (lane & 31);   // dk-local
            unsigned off = (unsigned)(row * 256 + (s6 * 64 + s4 * 16 + (lane >> 5) * 8) * 2);
            off ^= (row & 7) << 4;
            const bf16x8 v8 = *(const bf16x8*)(C + off);
            const int hh = xt * 2 + hhl;
            const unsigned chunk = ((msb >> 6) + s6) * 8 + od * 4 + s4;
            *(bf16x8*)(outp + (((size_t)(bb * NH + hh)) << 16) +
                       (size_t)chunk * 512 + lane * 8) = v8;
        }
    }
}

// ---------------------------------------------------------------------------
// Kernel 4: output projection GEMM (unchanged from R11, passing).
// ---------------------------------------------------------------------------
__global__ __launch_bounds__(256) void gemm_out(
    const unsigned short* __restrict__ Xb, const unsigned short* __restrict__ Wt,
    const float* __restrict__ bo, float* __restrict__ outp) {
    __shared__ unsigned short SM2[10240];
    const int t = threadIdx.x;
    const int lane = t & 63, w = t >> 6;
    const int wr = w >> 1, wc = w & 1;
    const int lr = lane & 15, lg = lane >> 4;
    const int bid = blockIdx.x;               // 1024 blocks
    const int u = (bid & 7) * 128 + (bid >> 3);
    const int xt = u & 7, yt = u >> 3;
    const int m0 = yt * 64, n0 = xt * 64;

    const int s_row = t >> 2;          // 0..63
    const int s_col = (t & 3) * 8;

    f32x4 acc[2][2];
    #pragma unroll
    for (int i = 0; i < 2; ++i)
        #pragma unroll
        for (int j = 0; j < 2; ++j) acc[i][j] = (f32x4){0.f, 0.f, 0.f, 0.f};

    bf16x8 raa, rbb;

#define OUT_LOAD(kt) do {                                                      \
        const int _k0 = (kt) * 32;                                             \
        raa = *(const bf16x8*)(Xb + (size_t)(m0 + s_row) * ND + _k0 + s_col);  \
        rbb = *(const bf16x8*)(Wt + (size_t)(n0 + s_row) * ND + _k0 + s_col);  \
    } while (0)

#define OUT_WRITE(p) do {                                                      \
        *(bf16x8*)(&SM2[(p) * 2560 + s_row * 40 + s_col]) = raa;               \
        *(bf16x8*)(&SM2[5120 + (p) * 2560 + s_row * 40 + s_col]) = rbb;        \
    } while (0)

#define OUT_COMPUTE(p) do {                                                    \
        bf16x8 af[2], bfr[2];                                                  \
        _Pragma("unroll")                                                      \
        for (int mi = 0; mi < 2; ++mi)                                         \
            af[mi] = *(const bf16x8*)(&SM2[(p) * 2560 + (wr * 32 + mi * 16 + lr) * 40 + lg * 8]); \
        _Pragma("unroll")                                                      \
        for (int nj = 0; nj < 2; ++nj)                                         \
            bfr[nj] = *(const bf16x8*)(&SM2[5120 + (p) * 2560 + (wc * 32 + nj * 16 + lr) * 40 + lg * 8]); \
        __builtin_amdgcn_s_setprio(1);                                         \
        _Pragma("unroll")                                                      \
        for (int mi = 0; mi < 2; ++mi)                                         \
            _Pragma("unroll")                                                  \
            for (int nj = 0; nj < 2; ++nj)                                     \
                acc[mi][nj] = __builtin_amdgcn_mfma_f32_16x16x32_bf16(         \
                    af[mi], bfr[nj], acc[mi][nj], 0, 0, 0);                    \
        __builtin_amdgcn_s_setprio(0);                                         \
    } while (0)

    OUT_LOAD(0);
    OUT_WRITE(0);
    OUT_LOAD(1);
    __syncthreads();
    #pragma unroll 1
    for (int kt = 0; kt < 15; ++kt) {
        OUT_COMPUTE(kt & 1);
        OUT_WRITE((kt + 1) & 1);
        if (kt < 14) OUT_LOAD(kt + 2);
        __syncthreads();
    }
    OUT_COMPUTE(1);
#undef OUT_LOAD
#undef OUT_WRITE
#undef OUT_COMPUTE

    #pragma unroll
    for (int mi = 0; mi < 2; ++mi) {
        #pragma unroll
        for (int nj = 0; nj < 2; ++nj) {
            const int n = n0 + wc * 32 + nj * 16 + lr;
            const float bv = bo[n];
            #pragma unroll
            for (int r = 0; r < 4; ++r) {
                const int m = m0 + wr * 32 + mi * 16 + lg * 4 + r;
                outp[(size_t)m * ND + n] = acc[mi][nj][r] + bv;
            }
        }
    }
}

// ---------------------------------------------------------------------------
// Kernel 3: flash attention (unchanged from R5-R11, passing).
// ---------------------------------------------------------------------------
struct AttnState {
    f32x16 acc0, acc1;
    float m_st, l_st;
};

__device__ __forceinline__ void attn_step(const bf16x8 (&kf)[8], const bf16x8 (&vv)[8],
                                          const bf16x8 (&qf)[4], int mval,
                                          float* __restrict__ brow, int lane, int hi,
                                          AttnState& st) {
    brow[lane] = mval ? 0.f : NEGBIG;

    f32x16 sc0 = {}, sc1 = {};
    __builtin_amdgcn_s_setprio(1);
    sc0 = __builtin_amdgcn_mfma_f32_32x32x16_bf16(kf[0], qf[0], sc0, 0, 0, 0);
    sc1 = __builtin_amdgcn_mfma_f32_32x32x16_bf16(kf[4], qf[0], sc1, 0, 0, 0);
    sc0 = __builtin_amdgcn_mfma_f32_32x32x16_bf16(kf[1], qf[1], sc0, 0, 0, 0);
    sc1 = __builtin_amdgcn_mfma_f32_32x32x16_bf16(kf[5], qf[1], sc1, 0, 0, 0);
    sc0 = __builtin_amdgcn_mfma_f32_32x32x16_bf16(kf[2], qf[2], sc0, 0, 0, 0);
    sc1 = __builtin_amdgcn_mfma_f32_32x32x16_bf16(kf[6], qf[2], sc1, 0, 0, 0);
    sc0 = __builtin_amdgcn_mfma_f32_32x32x16_bf16(kf[3], qf[3], sc0, 0, 0, 0);
    sc1 = __builtin_amdgcn_mfma_f32_32x32x16_bf16(kf[7], qf[3], sc1, 0, 0, 0);
    __builtin_amdgcn_s_setprio(0);

    {
        const float* bl = brow + 4 * hi;
        #pragma unroll
        for (int mm = 0; mm < 4; ++mm) {
            const f32x4 bv0 = *(const f32x4*)(bl + 8 * mm);
            const f32x4 bv1 = *(const f32x4*)(bl + 32 + 8 * mm);
            #pragma unroll
            for (int c = 0; c < 4; ++c) {
                sc0[4 * mm + c] += bv0[c];
                sc1[4 * mm + c] += bv1[c];
            }
        }
    }

    float tv[16];
    #pragma unroll
    for (int r = 0; r < 16; ++r) tv[r] = fmaxf(sc0[r], sc1[r]);
    #pragma unroll
    for (int s = 8; s > 0; s >>= 1)
        #pragma unroll
        for (int r = 0; r < 16; ++r)
            if (r < s) tv[r] = fmaxf(tv[r], tv[r + s]);
    const float mx = fmaxf(tv[0], __shfl_xor(tv[0], 32));
    const float mn = fmaxf(st.m_st, mx);

    #pragma unroll
    for (int r = 0; r < 16; ++r) {
        sc0[r] = __builtin_amdgcn_exp2f(sc0[r] - mn);
        sc1[r] = __builtin_amdgcn_exp2f(sc1[r] - mn);
    }
    #pragma unroll
    for (int r = 0; r < 16; ++r) tv[r] = sc0[r] + sc1[r];
    #pragma unroll
    for (int s = 8; s > 0; s >>= 1)
        #pragma unroll
        for (int r = 0; r < 16; ++r)
            if (r < s) tv[r] += tv[r + s];
    const float rs = tv[0] + __shfl_xor(tv[0], 32);

    const bool ch = mn > st.m_st;
    if (__any(ch)) {
        const float f = __builtin_amdgcn_exp2f(st.m_st - mn);
        st.l_st = st.l_st * f + rs;
        st.m_st = mn;
        #pragma unroll
        for (int r = 0; r < 16; ++r) { st.acc0[r] *= f; st.acc1[r] *= f; }
    } else {
        st.l_st += rs;
    }

    union U8 { unsigned u[4]; bf16x8 v; };
    bf16x8 pA0, pA1, pB0, pB1;
    {
        unsigned w00, w01, w10, w11, w20, w21, w30, w31;
        CVTPK(w00, sc0[0], sc0[1]);  CVTPK(w01, sc0[2], sc0[3]);
        CVTPK(w10, sc0[4], sc0[5]);  CVTPK(w11, sc0[6], sc0[7]);
        CVTPK(w20, sc0[8], sc0[9]);  CVTPK(w21, sc0[10], sc0[11]);
        CVTPK(w30, sc0[12], sc0[13]); CVTPK(w31, sc0[14], sc0[15]);
        PLSWAP(w00, w10); PLSWAP(w01, w11);
        PLSWAP(w20, w30); PLSWAP(w21, w31);
        U8 f0; f0.u[0] = w00; f0.u[1] = w01; f0.u[2] = w10; f0.u[3] = w11;
        U8 f1; f1.u[0] = w20; f1.u[1] = w21; f1.u[2] = w30; f1.u[3] = w31;
        pA0 = f0.v; pA1 = f1.v;
    }
    {
        unsigned w00, w01, w10, w11, w20, w21, w30, w31;
        CVTPK(w00, sc1[0], sc1[1]);  CVTPK(w01, sc1[2], sc1[3]);
        CVTPK(w10, sc1[4], sc1[5]);  CVTPK(w11, sc1[6], sc1[7]);
        CVTPK(w20, sc1[8], sc1[9]);  CVTPK(w21, sc1[10], sc1[11]);
        CVTPK(w30, sc1[12], sc1[13]); CVTPK(w31, sc1[14], sc1[15]);
        PLSWAP(w00, w10); PLSWAP(w01, w11);
        PLSWAP(w20, w30); PLSWAP(w21, w31);
        U8 f0; f0.u[0] = w00; f0.u[1] = w01; f0.u[2] = w10; f0.u[3] = w11;
        U8 f1; f1.u[0] = w20; f1.u[1] = w21; f1.u[2] = w30; f1.u[3] = w31;
        pB0 = f0.v; pB1 = f1.v;
    }

    __builtin_amdgcn_s_setprio(1);
    st.acc0 = __builtin_amdgcn_mfma_f32_32x32x16_bf16(vv[0], pA0, st.acc0, 0, 0, 0);
    st.acc1 = __builtin_amdgcn_mfma_f32_32x32x16_bf16(vv[4], pA0, st.acc1, 0, 0, 0);
    st.acc0 = __builtin_amdgcn_mfma_f32_32x32x16_bf16(vv[1], pA1, st.acc0, 0, 0, 0);
    st.acc1 = __builtin_amdgcn_mfma_f32_32x32x16_bf16(vv[5], pA1, st.acc1, 0, 0, 0);
    st.acc0 = __builtin_amdgcn_mfma_f32_32x32x16_bf16(vv[2], pB0, st.acc0, 0, 0, 0);
    st.acc1 = __builtin_amdgcn_mfma_f32_32x32x16_bf16(vv[6], pB0, st.acc1, 0, 0, 0);
    st.acc0 = __builtin_amdgcn_mfma_f32_32x32x16_bf16(vv[3], pB1, st.acc0, 0, 0, 0);
    st.acc1 = __builtin_amdgcn_mfma_f32_32x32x16_bf16(vv[7], pB1, st.acc1, 0, 0, 0);
    __builtin_amdgcn_s_setprio(0);
}

__global__ __launch_bounds__(256, 2) void attn_kernel(const unsigned short* __restrict__ QF,
                                                      const unsigned short* __restrict__ KF,
                                                      const unsigned short* __restrict__ VF,
                                                      const int* __restrict__ mask,
                                                      unsigned short* __restrict__ Xb) {
    __shared__ float bias_lds[4][64];
    const int t = threadIdx.x;
    const int lane = t & 63, w = t >> 6;
    const int q32 = lane & 31, hi = lane >> 5;
    const int bid = blockIdx.x;                  // 512 blocks
    const int u = (bid & 7) * 64 + (bid >> 3);
    const int bh = u >> 3, xq = u & 7;
    const int b = bh >> 3, h = bh & 7;
    const int q = xq * 128 + w * 32 + q32;
    const unsigned short* QFh = QF + ((size_t)bh << 16);
    const unsigned short* KFh = KF + ((size_t)bh << 16);
    const unsigned short* VFh = VF + ((size_t)bh << 16);
    const int* mk = mask + b * NS;
    float* brow = &bias_lds[w][0];

    bf16x8 qf[4];
    {
        const unsigned short* Qp = QFh + (size_t)(xq * 16 + w * 4) * 512 + lane * 8;
        qf[0] = *(const bf16x8*)(Qp + 0 * 512);
        qf[1] = *(const bf16x8*)(Qp + 1 * 512);
        qf[2] = *(const bf16x8*)(Qp + 2 * 512);
        qf[3] = *(const bf16x8*)(Qp + 3 * 512);
    }

    AttnState st;
    st.acc0 = (f32x16){}; st.acc1 = (f32x16){};
    st.m_st = -1.0e30f; st.l_st = 0.f;

    bf16x8 kA[8], kB[8], vv[8];

#define LOADK(dst, itx) do {                                                   \
        const unsigned short* _p = KFh + (size_t)(itx) * 4096 + lane * 8;      \
        dst[0] = *(const bf16x8*)(_p + 0 * 512);                               \
        dst[1] = *(const bf16x8*)(_p + 1 * 512);                               \
        dst[2] = *(const bf16x8*)(_p + 2 * 512);                               \
        dst[3] = *(const bf16x8*)(_p + 3 * 512);                               \
        dst[4] = *(const bf16x8*)(_p + 4 * 512);                               \
        dst[5] = *(const bf16x8*)(_p + 5 * 512);                               \
        dst[6] = *(const bf16x8*)(_p + 6 * 512);                               \
        dst[7] = *(const bf16x8*)(_p + 7 * 512);                               \
    } while (0)

#define LOADV(dst, itx) do {                                                   \
        const unsigned short* _p = VFh + (size_t)(itx) * 4096 + lane * 8;      \
        dst[0] = *(const bf16x8*)(_p + 0 * 512);                               \
        dst[1] = *(const bf16x8*)(_p + 1 * 512);                               \
        dst[2] = *(const bf16x8*)(_p + 2 * 512);                               \
        dst[3] = *(const bf16x8*)(_p + 3 * 512);                               \
        dst[4] = *(const bf16x8*)(_p + 4 * 512);                               \
        dst[5] = *(const bf16x8*)(_p + 5 * 512);                               \
        dst[6] = *(const bf16x8*)(_p + 6 * 512);                               \
        dst[7] = *(const bf16x8*)(_p + 7 * 512);                               \
    } while (0)

    LOADK(kA, 0);
    #pragma unroll 1
    for (int ii = 0; ii < 8; ++ii) {
        const int itE = ii * 2, itO = itE + 1;
        const int mE = mk[itE * 64 + lane];
        LOADV(vv, itE);
        LOADK(kB, itO);
        __builtin_amdgcn_sched_barrier(0);
        attn_step(kA, vv, qf, mE, brow, lane, hi, st);
        const int mO = mk[itO * 64 + lane];
        const int itN = itO + 1 > 15 ? 15 : itO + 1;
        LOADV(vv, itO);
        LOADK(kA, itN);
        __builtin_amdgcn_sched_barrier(0);
        attn_step(kB, vv, qf, mO, brow, lane, hi, st);
    }
#undef LOADK
#undef LOADV

    const float inv = st.l_st > 0.f ? 1.f / st.l_st : 0.f;
    unsigned short* Xp = Xb + (size_t)(b * NS + q) * ND + h * 64 + 4 * hi;
    #pragma unroll
    for (int mm = 0; mm < 4; ++mm) {
        unsigned w0, w1;
        CVTPK(w0, st.acc0[4 * mm] * inv, st.acc0[4 * mm + 1] * inv);
        CVTPK(w1, st.acc0[4 * mm + 2] * inv, st.acc0[4 * mm + 3] * inv);
        uint2 pv; pv.x = w0; pv.y = w1;
        *(uint2*)(Xp + 8 * mm) = pv;
        CVTPK(w0, st.acc1[4 * mm] * inv, st.acc1[4 * mm + 1] * inv);
        CVTPK(w1, st.acc1[4 * mm + 2] * inv, st.acc1[4 * mm + 3] * inv);
        pv.x = w0; pv.y = w1;
        *(uint2*)(Xp + 32 + 8 * mm) = pv;
    }
}

// ---------------------------------------------------------------------------
// Host launcher. Workspace (bf16 elements): wt(4*512*512), QF, KF, VF, Xb.
// ---------------------------------------------------------------------------
extern "C" void kernel_launch(void* const* d_in, const int* in_sizes, int n_in,
                              void* d_out, int out_size, void* d_ws, size_t ws_size,
                              hipStream_t stream) {
    const float* query = (const float*)d_in[0];
    const float* key   = (const float*)d_in[1];
    const float* value = (const float*)d_in[2];
    const int*   mask  = (const int*)d_in[3];
    const float* Wq = (const float*)d_in[4];
    const float* bq = (const float*)d_in[5];
    const float* Wk = (const float*)d_in[6];
    const float* bk = (const float*)d_in[7];
    const float* Wv = (const float*)d_in[8];
    const float* bv = (const float*)d_in[9];
    const float* Wo = (const float*)d_in[10];
    const float* bo = (const float*)d_in[11];

    const size_t HEADSZ = (size_t)NB * NH * NS * NDK;  // 4194304
    unsigned short* wt = (unsigned short*)d_ws;
    unsigned short* QFb = wt + (size_t)4 * ND * ND;
    unsigned short* KFb = QFb + HEADSZ;
    unsigned short* VFb = KFb + HEADSZ;
    unsigned short* Xb  = VFb + HEADSZ;

    // 1. weights -> bf16, transposed
    wt_kernel<<<dim3(8, 8, 4), 256, 0, stream>>>(Wq, Wk, Wv, Wo, wt);

    // 2. QKV projections into fragment-major layouts (grid.y = z; BK=64)
    gemm_qkv<<<dim3(256, 3), 256, 0, stream>>>(query, key, value, wt, bq, bk, bv, QFb);

    // 3. attention (512 blocks, 4 waves each, no barriers)
    attn_kernel<<<512, 256, 0, stream>>>(QFb, KFb, VFb, mask, Xb);

    // 4. output projection (fp32 out)
    gemm_out<<<1024, 256, 0, stream>>>(Xb, wt + (size_t)3 * ND * ND, bo, (float*)d_out);
}